// Round 1
// baseline (331.560 us; speedup 1.0000x reference)
//
#include <hip/hip_runtime.h>

typedef __bf16 bf16x8 __attribute__((ext_vector_type(8)));
typedef float  f32x4  __attribute__((ext_vector_type(4)));

#define DEV static __device__ __forceinline__

// ---------- helpers ----------

DEV ushort f2bf(float f) {
    uint u = __builtin_bit_cast(uint, f);
    u = u + 0x7fffu + ((u >> 16) & 1u);
    return (ushort)(u >> 16);
}

// Stage an [nrows][64] bf16 tile (row stride gstride elems) from global into LDS
// via global_load_lds width=16, linear LDS layout, with the inverse XOR swizzle
// applied on the GLOBAL source column so that swizzled reads get correct data.
// nchunks = nrows*8 (16B chunks). Block = 256 threads.
DEV void stage_swz(const ushort* g, int gstride, char* lds, int nchunks) {
    const int tid  = threadIdx.x;
    const int lane = tid & 63;
    const int wave = tid >> 6;
    for (int c0 = wave * 64; c0 < nchunks; c0 += 256) {
        int c   = c0 + lane;
        int row = c >> 3;
        int cc  = (c & 7) ^ (row & 7);          // inverse swizzle on source
        const ushort* src = g + row * gstride + cc * 8;
        __builtin_amdgcn_global_load_lds((__attribute__((address_space(1))) void*)src,
                                         (__attribute__((address_space(3))) void*)(lds + c0 * 16),
                                         16, 0, 0);
    }
}

// Swizzled 16B fragment read: logical (row, 16B-chunk kc) of a [*][64] bf16 tile.
DEV bf16x8 ldfrag(const char* tile, int row, int kc) {
    int off = (row << 7) + (((kc) ^ (row & 7)) << 4);
    return *(const bf16x8*)(tile + off);
}

// ---------- fp32 -> bf16 conversion ----------

struct CvtArgs { const float* s[4]; ushort* d[4]; int n; };

__global__ void cvt_kernel(CvtArgs a) {
    const float* __restrict__ s = a.s[blockIdx.y];
    ushort* __restrict__ d = a.d[blockIdx.y];
    const int stride = gridDim.x * blockDim.x;
    for (int i = blockIdx.x * blockDim.x + threadIdx.x; i * 8 < a.n; i += stride) {
        const float4* p = (const float4*)(s + (size_t)i * 8);
        float4 x = p[0], y = p[1];
        uint4 o;
        o.x = (uint)f2bf(x.x) | ((uint)f2bf(x.y) << 16);
        o.y = (uint)f2bf(x.z) | ((uint)f2bf(x.w) << 16);
        o.z = (uint)f2bf(y.x) | ((uint)f2bf(y.y) << 16);
        o.w = (uint)f2bf(y.z) | ((uint)f2bf(y.w) << 16);
        *(uint4*)(d + (size_t)i * 8) = o;
    }
}

// ---------- GEMM: y = A[M,K] @ W[N,K]^T, bf16 in, epilogue per MODE ----------
// MODE 0: bf16 out, layout [B,H,S,DK], value*scale   (Q with scale=0.125, K with 1.0)
// MODE 1: bf16 out, layout [B,H,DK,S]                (V transposed)
// MODE 2: fp32 out, layout [M,N]                     (final projection)
// Tile: BM=128, BN=64, BK=64. 256 threads = 4 waves (2x2), wave tile 64x32.

constexpr int GM = 4096, GN = 1024, GK = 1024;

template<int MODE>
__global__ __launch_bounds__(256) void gemm_bt(const ushort* __restrict__ A,
                                               const ushort* __restrict__ W,
                                               void* __restrict__ Out, float scale) {
    __shared__ char smem[128 * 128 * 2 + 64 * 128];  // As 16KB + Ws 8KB
    char* As = smem;
    char* Ws = smem + 16384;
    const int tid  = threadIdx.x;
    const int lane = tid & 63;
    const int w    = tid >> 6;
    const int wr   = w >> 1, wc = w & 1;
    const int hi   = lane >> 4, lj = lane & 15;
    const int bid  = blockIdx.x;
    const int nb   = bid & 15, mb = bid >> 4;   // 32 x 16 grid

    f32x4 acc[4][2];
#pragma unroll
    for (int mi = 0; mi < 4; mi++)
#pragma unroll
        for (int ni = 0; ni < 2; ni++) acc[mi][ni] = f32x4{0.f, 0.f, 0.f, 0.f};

    const ushort* Ag = A + (size_t)mb * 128 * GK;
    const ushort* Wg = W + (size_t)nb * 64 * GK;

    for (int k0 = 0; k0 < GK; k0 += 64) {
        __syncthreads();
        stage_swz(Ag + k0, GK, As, 1024);
        stage_swz(Wg + k0, GK, Ws, 512);
        __syncthreads();
#pragma unroll
        for (int kk = 0; kk < 2; ++kk) {
            bf16x8 a[4], b[2];
#pragma unroll
            for (int mi = 0; mi < 4; mi++) a[mi] = ldfrag(As, wr * 64 + mi * 16 + lj, kk * 4 + hi);
#pragma unroll
            for (int ni = 0; ni < 2; ni++) b[ni] = ldfrag(Ws, wc * 32 + ni * 16 + lj, kk * 4 + hi);
#pragma unroll
            for (int mi = 0; mi < 4; mi++)
#pragma unroll
                for (int ni = 0; ni < 2; ni++)
                    acc[mi][ni] = __builtin_amdgcn_mfma_f32_16x16x32_bf16(a[mi], b[ni], acc[mi][ni], 0, 0, 0);
        }
    }

#pragma unroll
    for (int mi = 0; mi < 4; mi++) {
#pragma unroll
        for (int r = 0; r < 4; r++) {
            const int gm = mb * 128 + wr * 64 + mi * 16 + hi * 4 + r;
#pragma unroll
            for (int ni = 0; ni < 2; ni++) {
                const int gn = nb * 64 + wc * 32 + ni * 16 + lj;
                float v = acc[mi][ni][r] * scale;
                if constexpr (MODE == 2) {
                    ((float*)Out)[(size_t)gm * GN + gn] = v;
                } else {
                    const int b_ = gm >> 11, s_ = gm & 2047;
                    const int h_ = gn >> 6,  d_ = gn & 63;
                    size_t off;
                    if constexpr (MODE == 0) off = (((size_t)b_ * 16 + h_) * 2048 + s_) * 64 + d_;
                    else                     off = (((size_t)b_ * 16 + h_) * 64 + d_) * 2048 + s_;
                    ((ushort*)Out)[off] = f2bf(v);
                }
            }
        }
    }
}

// ---------- Flash attention (causal), per (b,h) ----------
// Q [B,H,S,64] bf16 (pre-scaled by 0.125), K [B,H,S,64] bf16, Vt [B,H,64,S] bf16.
// Block: 128 Q rows, 4 waves x 32 rows. KV tiles of 64. Online softmax in regs.

__global__ __launch_bounds__(256) void attn_kernel(const ushort* __restrict__ Qb,
                                                   const ushort* __restrict__ Kb,
                                                   const ushort* __restrict__ Vt,
                                                   ushort* __restrict__ Xb) {
    constexpr int S = 2048;
    __shared__ char smem[16384 + 8192 + 8192 + 4 * 4608];
    char* Qs = smem;
    char* Ks = smem + 16384;
    char* Vs = smem + 24576;
    const int tid = threadIdx.x, lane = tid & 63, w = tid >> 6;
    char* Pw = smem + 32768 + w * 4608;            // per-wave P tile [32][72] bf16
    ushort* Pwu = (ushort*)Pw;
    const int hi = lane >> 4, lj = lane & 15;
    const int qt = blockIdx.x, bh = blockIdx.y;
    const int q0 = qt * 128;

    const ushort* Qg = Qb + (size_t)bh * S * 64 + (size_t)q0 * 64;
    const ushort* Kg = Kb + (size_t)bh * S * 64;
    const ushort* Vg = Vt + (size_t)bh * 64 * S;

    stage_swz(Qg, 64, Qs, 1024);   // completion guaranteed by first in-loop barrier

    f32x4 o[2][4];
    float m_run[2][4], l_run[2][4];
#pragma unroll
    for (int mi = 0; mi < 2; mi++)
#pragma unroll
        for (int ni = 0; ni < 4; ni++) o[mi][ni] = f32x4{0.f, 0.f, 0.f, 0.f};
#pragma unroll
    for (int mi = 0; mi < 2; mi++)
#pragma unroll
        for (int r = 0; r < 4; r++) { m_run[mi][r] = -1e30f; l_run[mi][r] = 0.f; }

    const int ntiles = qt * 2 + 2;
    for (int kt = 0; kt < ntiles; ++kt) {
        __syncthreads();
        stage_swz(Kg + (size_t)kt * 64 * 64, 64, Ks, 512);
        stage_swz(Vg + kt * 64, S, Vs, 512);
        __syncthreads();

        if (kt * 64 <= q0 + w * 32 + 31) {          // wave-uniform causal skip
            // ---- S = Q K^T ----
            f32x4 sc[2][4];
#pragma unroll
            for (int mi = 0; mi < 2; mi++)
#pragma unroll
                for (int ni = 0; ni < 4; ni++) sc[mi][ni] = f32x4{0.f, 0.f, 0.f, 0.f};
#pragma unroll
            for (int kk = 0; kk < 2; ++kk) {
                bf16x8 aq[2], bk[4];
#pragma unroll
                for (int mi = 0; mi < 2; mi++) aq[mi] = ldfrag(Qs, w * 32 + mi * 16 + lj, kk * 4 + hi);
#pragma unroll
                for (int ni = 0; ni < 4; ni++) bk[ni] = ldfrag(Ks, ni * 16 + lj, kk * 4 + hi);
#pragma unroll
                for (int mi = 0; mi < 2; mi++)
#pragma unroll
                    for (int ni = 0; ni < 4; ni++)
                        sc[mi][ni] = __builtin_amdgcn_mfma_f32_16x16x32_bf16(aq[mi], bk[ni], sc[mi][ni], 0, 0, 0);
            }

            const bool diag = (kt >= qt * 2);
            // ---- online softmax (per q-row; row lives in 16 lanes x 4 frags) ----
#pragma unroll
            for (int mi = 0; mi < 2; mi++) {
#pragma unroll
                for (int r = 0; r < 4; r++) {
                    const int qrow = q0 + w * 32 + mi * 16 + hi * 4 + r;
                    float s4[4];
                    float tmax = -1e30f;
#pragma unroll
                    for (int ni = 0; ni < 4; ni++) {
                        float sv = sc[mi][ni][r];
                        if (diag && (kt * 64 + ni * 16 + lj > qrow)) sv = -1e30f;
                        s4[ni] = sv;
                        tmax = fmaxf(tmax, sv);
                    }
#pragma unroll
                    for (int off = 1; off < 16; off <<= 1) tmax = fmaxf(tmax, __shfl_xor(tmax, off));
                    const float mo = m_run[mi][r];
                    const float mn = fmaxf(mo, tmax);
                    const float rescale = __expf(mo - mn);
                    m_run[mi][r] = mn;
                    float psum = 0.f;
#pragma unroll
                    for (int ni = 0; ni < 4; ni++) {
                        float p = __expf(s4[ni] - mn);
                        psum += p;
                        Pwu[(mi * 16 + hi * 4 + r) * 72 + ni * 16 + lj] = f2bf(p);
                    }
#pragma unroll
                    for (int off = 1; off < 16; off <<= 1) psum += __shfl_xor(psum, off);
                    l_run[mi][r] = l_run[mi][r] * rescale + psum;
#pragma unroll
                    for (int ni = 0; ni < 4; ni++) o[mi][ni][r] *= rescale;
                }
            }

            // make this wave's P writes visible to its own cross-lane reads
            asm volatile("s_waitcnt lgkmcnt(0)" ::: "memory");

            // ---- O += P V ----
#pragma unroll
            for (int kk = 0; kk < 2; ++kk) {
                bf16x8 pa[2], bv[4];
#pragma unroll
                for (int mi = 0; mi < 2; mi++)
                    pa[mi] = *(const bf16x8*)(Pw + ((mi * 16 + lj) * 72 + (kk * 4 + hi) * 8) * 2);
#pragma unroll
                for (int ni = 0; ni < 4; ni++) bv[ni] = ldfrag(Vs, ni * 16 + lj, kk * 4 + hi);
#pragma unroll
                for (int mi = 0; mi < 2; mi++)
#pragma unroll
                    for (int ni = 0; ni < 4; ni++)
                        o[mi][ni] = __builtin_amdgcn_mfma_f32_16x16x32_bf16(pa[mi], bv[ni], o[mi][ni], 0, 0, 0);
            }
        }
    }

    // ---- epilogue: x[b, s, h*64 + d] = O / l ----
    const int b_ = bh >> 4, h_ = bh & 15;
#pragma unroll
    for (int mi = 0; mi < 2; mi++) {
#pragma unroll
        for (int r = 0; r < 4; r++) {
            const float inv = 1.f / l_run[mi][r];
            const int srow = q0 + w * 32 + mi * 16 + hi * 4 + r;
#pragma unroll
            for (int ni = 0; ni < 4; ni++) {
                Xb[((size_t)b_ * S + srow) * 1024 + h_ * 64 + ni * 16 + lj] =
                    f2bf(o[mi][ni][r] * inv);
            }
        }
    }
}

// ---------- launch ----------

extern "C" void kernel_launch(void* const* d_in, const int* in_sizes, int n_in,
                              void* d_out, int out_size, void* d_ws, size_t ws_size,
                              hipStream_t stream) {
    (void)in_sizes; (void)n_in; (void)out_size; (void)ws_size;
    const float* q  = (const float*)d_in[0];
    const float* k  = (const float*)d_in[1];
    const float* v  = (const float*)d_in[2];
    // d_in[3] = mask (causal tril) — computed analytically
    const float* Wq = (const float*)d_in[4];
    const float* Wk = (const float*)d_in[5];
    const float* Wv = (const float*)d_in[6];
    const float* Wo = (const float*)d_in[7];

    char* ws = (char*)d_ws;
    const size_t MB = (size_t)1 << 20;
    ushort* Qb  = (ushort*)(ws + 0 * MB);    // [2,16,2048,64] bf16  (8 MB)
    ushort* Kb  = (ushort*)(ws + 8 * MB);    // [2,16,2048,64] bf16  (8 MB)
    ushort* Vtb = (ushort*)(ws + 16 * MB);   // [2,16,64,2048] bf16  (8 MB)
    ushort* Xb  = (ushort*)(ws + 24 * MB);   // [4096,1024]    bf16  (8 MB)
    ushort* qb  = (ushort*)(ws + 32 * MB);
    ushort* kb  = (ushort*)(ws + 40 * MB);
    ushort* vb  = (ushort*)(ws + 48 * MB);
    ushort* Wqb = (ushort*)(ws + 56 * MB);
    ushort* Wkb = (ushort*)(ws + 58 * MB);
    ushort* Wvb = (ushort*)(ws + 60 * MB);
    ushort* Wob = (ushort*)(ws + 62 * MB);

    CvtArgs c1;
    c1.s[0] = q;  c1.s[1] = k;  c1.s[2] = v;  c1.s[3] = q;
    c1.d[0] = qb; c1.d[1] = kb; c1.d[2] = vb; c1.d[3] = qb;
    c1.n = 4 * 1024 * 1024;
    cvt_kernel<<<dim3(2048, 3), 256, 0, stream>>>(c1);

    CvtArgs c2;
    c2.s[0] = Wq;  c2.s[1] = Wk;  c2.s[2] = Wv;  c2.s[3] = Wo;
    c2.d[0] = Wqb; c2.d[1] = Wkb; c2.d[2] = Wvb; c2.d[3] = Wob;
    c2.n = 1024 * 1024;
    cvt_kernel<<<dim3(512, 4), 256, 0, stream>>>(c2);

    gemm_bt<0><<<512, 256, 0, stream>>>(qb, Wqb, (void*)Qb, 0.125f);  // Q, pre-scaled 1/sqrt(dk)
    gemm_bt<0><<<512, 256, 0, stream>>>(kb, Wkb, (void*)Kb, 1.0f);    // K
    gemm_bt<1><<<512, 256, 0, stream>>>(vb, Wvb, (void*)Vtb, 1.0f);   // V (transposed out)

    attn_kernel<<<dim3(16, 32), 256, 0, stream>>>(Qb, Kb, Vtb, Xb);

    gemm_bt<2><<<512, 256, 0, stream>>>(Xb, Wob, d_out, 1.0f);        // final projection, fp32 out
}

// Round 3
// 282.763 us; speedup vs baseline: 1.1726x; 1.1726x over previous
//
#include <hip/hip_runtime.h>

typedef __bf16 bf16x8 __attribute__((ext_vector_type(8)));
typedef float  f32x4  __attribute__((ext_vector_type(4)));

#define DEV static __device__ __forceinline__
#define VMCNT(n) asm volatile("s_waitcnt vmcnt(" #n ")" ::: "memory")
#define LGKM0()  asm volatile("s_waitcnt lgkmcnt(0)" ::: "memory")
#define SBAR()   __builtin_amdgcn_s_barrier()
#define SFENCE() __builtin_amdgcn_sched_barrier(0)

// ---------- helpers ----------

DEV ushort f2bf(float f) {
    uint u = __builtin_bit_cast(uint, f);
    u = u + 0x7fffu + ((u >> 16) & 1u);
    return (ushort)(u >> 16);
}

// Stage an [nrows][64] bf16 tile (row stride gstride elems) into LDS via
// global_load_lds width=16; linear LDS dest, inverse-XOR-swizzled global source.
DEV void stage_swz(const ushort* g, int gstride, char* lds, int nchunks) {
    const int tid  = threadIdx.x;
    const int lane = tid & 63;
    const int wave = tid >> 6;
    for (int c0 = wave * 64; c0 < nchunks; c0 += 256) {
        int c   = c0 + lane;
        int row = c >> 3;
        int cc  = (c & 7) ^ (row & 7);
        const ushort* src = g + row * gstride + cc * 8;
        __builtin_amdgcn_global_load_lds((__attribute__((address_space(1))) void*)src,
                                         (__attribute__((address_space(3))) void*)(lds + c0 * 16),
                                         16, 0, 0);
    }
}

// Swizzled 16B fragment read: logical (row, 16B-chunk kc) of a [*][64] bf16 tile.
DEV bf16x8 ldfrag(const char* tile, int row, int kc) {
    int off = (row << 7) + ((kc ^ (row & 7)) << 4);
    return *(const bf16x8*)(tile + off);
}

// ---------- fp32 -> bf16 conversion (all 7 tensors, one dispatch) ----------

struct CvtArgs { const float* s[7]; ushort* d[7]; int n[7]; };

__global__ void cvt_kernel(CvtArgs a) {
    const int y = blockIdx.y;
    const float* __restrict__ s = a.s[y];
    ushort* __restrict__ d = a.d[y];
    const int n = a.n[y];
    const int stride = gridDim.x * blockDim.x;
    for (int i = blockIdx.x * blockDim.x + threadIdx.x; i * 8 < n; i += stride) {
        const float4* p = (const float4*)(s + (size_t)i * 8);
        float4 x = p[0], yv = p[1];
        uint4 o;
        o.x = (uint)f2bf(x.x)  | ((uint)f2bf(x.y)  << 16);
        o.y = (uint)f2bf(x.z)  | ((uint)f2bf(x.w)  << 16);
        o.z = (uint)f2bf(yv.x) | ((uint)f2bf(yv.y) << 16);
        o.w = (uint)f2bf(yv.z) | ((uint)f2bf(yv.w) << 16);
        *(uint4*)(d + (size_t)i * 8) = o;
    }
}

// ---------- GEMM core: y = A[4096,1024] @ W[1024,1024]^T ----------
// BM=128 BN=64 BK=64, 4 waves (2x2), double-buffered LDS, counted vmcnt.

constexpr int GN = 1024, GK = 1024;

template<typename EPI>
DEV void gemm_body(const ushort* __restrict__ A, const ushort* __restrict__ W,
                   char* smem, EPI epi) {
    char* As[2] = { smem,         smem + 16384 };
    char* Ws[2] = { smem + 32768, smem + 40960 };
    const int tid  = threadIdx.x;
    const int lane = tid & 63;
    const int w    = tid >> 6;
    const int wr   = w >> 1, wc = w & 1;
    const int hi   = lane >> 4, lj = lane & 15;
    const int bid  = blockIdx.x;
    const int nb   = bid & 15, mb = bid >> 4;   // 16 n-tiles x 32 m-tiles

    f32x4 acc[4][2];
#pragma unroll
    for (int mi = 0; mi < 4; mi++)
#pragma unroll
        for (int ni = 0; ni < 2; ni++) acc[mi][ni] = f32x4{0.f, 0.f, 0.f, 0.f};

    const ushort* Ag = A + (size_t)mb * 128 * GK;
    const ushort* Wg = W + (size_t)nb * 64 * GK;

    stage_swz(Ag, GK, As[0], 1024);
    stage_swz(Wg, GK, Ws[0], 512);
    int cur = 0;
    for (int k0 = 0; k0 < GK; k0 += 64) {
        if (k0 + 64 < GK) {
            stage_swz(Ag + k0 + 64, GK, As[cur ^ 1], 1024);
            stage_swz(Wg + k0 + 64, GK, Ws[cur ^ 1], 512);
            VMCNT(6);
        } else {
            VMCNT(0);
        }
        SBAR(); SFENCE();
#pragma unroll
        for (int kk = 0; kk < 2; ++kk) {
            bf16x8 a[4], b[2];
#pragma unroll
            for (int mi = 0; mi < 4; mi++) a[mi] = ldfrag(As[cur], wr * 64 + mi * 16 + lj, kk * 4 + hi);
#pragma unroll
            for (int ni = 0; ni < 2; ni++) b[ni] = ldfrag(Ws[cur], wc * 32 + ni * 16 + lj, kk * 4 + hi);
#pragma unroll
            for (int mi = 0; mi < 4; mi++)
#pragma unroll
                for (int ni = 0; ni < 2; ni++)
                    acc[mi][ni] = __builtin_amdgcn_mfma_f32_16x16x32_bf16(a[mi], b[ni], acc[mi][ni], 0, 0, 0);
        }
        LGKM0();
        SBAR(); SFENCE();
        cur ^= 1;
    }

#pragma unroll
    for (int mi = 0; mi < 4; mi++)
#pragma unroll
        for (int r = 0; r < 4; r++) {
            const int gm = mb * 128 + wr * 64 + mi * 16 + hi * 4 + r;
#pragma unroll
            for (int ni = 0; ni < 2; ni++) {
                const int gn = nb * 64 + wc * 32 + ni * 16 + lj;
                epi(gm, gn, acc[mi][ni][r]);
            }
        }
}

struct ProjArgs {
    const ushort* A[3]; const ushort* W[3]; ushort* O[3];
    float scale[3]; int mode[3];
};

__global__ __launch_bounds__(256) void gemm_proj(ProjArgs args) {
    __shared__ char smem[49152];
    const int z = blockIdx.z;
    const ushort* A = args.A[z];
    const ushort* W = args.W[z];
    ushort* Out = args.O[z];
    const float scale = args.scale[z];
    const int mode = args.mode[z];
    gemm_body(A, W, smem, [&](int gm, int gn, float v) {
        v *= scale;
        const int b_ = gm >> 11, s_ = gm & 2047;
        const int h_ = gn >> 6,  d_ = gn & 63;
        size_t off;
        if (mode == 0) off = (((size_t)b_ * 16 + h_) * 2048 + s_) * 64 + d_;
        else           off = (((size_t)b_ * 16 + h_) * 64 + d_) * 2048 + s_;
        Out[off] = f2bf(v);
    });
}

__global__ __launch_bounds__(256) void gemm_out(const ushort* __restrict__ A,
                                                const ushort* __restrict__ W,
                                                float* __restrict__ Out) {
    __shared__ char smem[49152];
    gemm_body(A, W, smem, [&](int gm, int gn, float v) {
        Out[(size_t)gm * GN + gn] = v;
    });
}

// ---------- Flash attention (causal), swapped QK^T, in-lane softmax ----------
// Q [B,H,S,64] bf16 (pre-scaled 0.125) held in registers; K,V^T double-buffered
// in LDS; per-wave P tile [32 q][64 kv] bf16 (XOR-swizzled). 4 waves x 32 q rows.
// Complement-pair qt remap balances causal work across CUs.

__global__ __launch_bounds__(256) void attn_kernel(const ushort* __restrict__ Qb,
                                                   const ushort* __restrict__ Kb,
                                                   const ushort* __restrict__ Vt,
                                                   ushort* __restrict__ Xb) {
    constexpr int S = 2048;
    __shared__ char smem[49152];
    const int tid = threadIdx.x, lane = tid & 63, w = tid >> 6;
    const int hi = lane >> 4, lj = lane & 15;
    char* Pw = smem + 32768 + w * 4096;   // per-wave [32][64] bf16, swizzled
    const int bh = blockIdx.x;
    const int yraw = blockIdx.y;
    const int qt = (yraw < 8) ? yraw : 23 - yraw;   // pair (y, 15-y) per CU
    const int q0 = qt * 128;
    const int q0w = q0 + w * 32;

    const ushort* Qg = Qb + (size_t)bh * S * 64;
    const ushort* Kg = Kb + (size_t)bh * S * 64;
    const ushort* Vg = Vt + (size_t)bh * 64 * S;

    // Q fragments in registers: q = q0w + mi*16 + lj, k = kk*32 + hi*8 + [0..8)
    bf16x8 qf[2][2];
#pragma unroll
    for (int mi = 0; mi < 2; mi++)
#pragma unroll
        for (int kk = 0; kk < 2; kk++)
            qf[mi][kk] = *(const bf16x8*)(Qg + (size_t)(q0w + mi * 16 + lj) * 64 + kk * 32 + hi * 8);

    f32x4 o[2][4];
    float m_run[2] = { -1e30f, -1e30f }, l_run[2] = { 0.f, 0.f };
#pragma unroll
    for (int mi = 0; mi < 2; mi++)
#pragma unroll
        for (int nd = 0; nd < 4; nd++) o[mi][nd] = f32x4{0.f, 0.f, 0.f, 0.f};

    const int nt = qt * 2 + 2;
    stage_swz(Kg, 64, smem, 512);
    stage_swz(Vg, S, smem + 16384, 512);
    int cur = 0;

    for (int t = 0; t < nt; ++t) {
        char* Kc = smem + (cur << 13);
        char* Vc = smem + 16384 + (cur << 13);
        if (t + 1 < nt) {
            stage_swz(Kg + (size_t)(t + 1) * 64 * 64, 64, smem + ((cur ^ 1) << 13), 512);
            stage_swz(Vg + (t + 1) * 64, S, smem + 16384 + ((cur ^ 1) << 13), 512);
            VMCNT(4);
        } else {
            VMCNT(0);
        }
        SBAR(); SFENCE();

        if (t * 64 <= q0w + 31) {                 // wave-uniform causal skip
            // ---- S^T = mfma(K, Q): lane holds S[kv=ni*16+hi*4+r][q=mi*16+lj] ----
            f32x4 sc[2][4];
#pragma unroll
            for (int mi = 0; mi < 2; mi++)
#pragma unroll
                for (int ni = 0; ni < 4; ni++) sc[mi][ni] = f32x4{0.f, 0.f, 0.f, 0.f};
            __builtin_amdgcn_s_setprio(1);
#pragma unroll
            for (int kk = 0; kk < 2; ++kk) {
                bf16x8 kf[4];
#pragma unroll
                for (int ni = 0; ni < 4; ni++) kf[ni] = ldfrag(Kc, ni * 16 + lj, kk * 4 + hi);
#pragma unroll
                for (int mi = 0; mi < 2; mi++)
#pragma unroll
                    for (int ni = 0; ni < 4; ni++)
                        sc[mi][ni] = __builtin_amdgcn_mfma_f32_16x16x32_bf16(kf[ni], qf[mi][kk], sc[mi][ni], 0, 0, 0);
            }
            __builtin_amdgcn_s_setprio(0);

            const bool diag = (t * 64 + 63 > q0w);
#pragma unroll
            for (int mi = 0; mi < 2; mi++) {
                const int q = q0w + mi * 16 + lj;
                if (diag) {
#pragma unroll
                    for (int ni = 0; ni < 4; ni++)
#pragma unroll
                        for (int r = 0; r < 4; r++)
                            if (t * 64 + ni * 16 + hi * 4 + r > q) sc[mi][ni][r] = -1e30f;
                }
                float mx = -1e30f;
#pragma unroll
                for (int ni = 0; ni < 4; ni++)
#pragma unroll
                    for (int r = 0; r < 4; r++) mx = fmaxf(mx, sc[mi][ni][r]);
                mx = fmaxf(mx, __shfl_xor(mx, 16));
                mx = fmaxf(mx, __shfl_xor(mx, 32));
                const float mo = m_run[mi];
                const float mn = fmaxf(mo, mx);
                const float rs = __expf(mo - mn);
                m_run[mi] = mn;
                float ps = 0.f;
                const int row = mi * 16 + lj;
#pragma unroll
                for (int ni = 0; ni < 4; ni++) {
                    float p0 = __expf(sc[mi][ni][0] - mn);
                    float p1 = __expf(sc[mi][ni][1] - mn);
                    float p2 = __expf(sc[mi][ni][2] - mn);
                    float p3 = __expf(sc[mi][ni][3] - mn);
                    ps += (p0 + p1) + (p2 + p3);
                    uint lo  = (uint)f2bf(p0) | ((uint)f2bf(p1) << 16);
                    uint hi2 = (uint)f2bf(p2) | ((uint)f2bf(p3) << 16);
                    const int c = ni * 2 + (hi >> 1);
                    uint2 pv; pv.x = lo; pv.y = hi2;
                    *(uint2*)(Pw + row * 128 + ((c ^ (row & 7)) << 4) + ((hi & 1) << 3)) = pv;
                }
                ps += __shfl_xor(ps, 16);
                ps += __shfl_xor(ps, 32);
                l_run[mi] = l_run[mi] * rs + ps;
                // broadcast rescale to O-layout rows (q = mi*16 + hi*4 + r)
#pragma unroll
                for (int r = 0; r < 4; r++) {
                    float rr = __shfl(rs, (lane & 48) | (hi * 4 + r));
#pragma unroll
                    for (int nd = 0; nd < 4; nd++) o[mi][nd][r] *= rr;
                }
            }

            LGKM0(); SFENCE();   // P writes visible to cross-lane reads

            // ---- O += P V : mfma(P rows q, Vt rows d) ----
            __builtin_amdgcn_s_setprio(1);
#pragma unroll
            for (int kk = 0; kk < 2; ++kk) {
                bf16x8 pa[2], bv[4];
#pragma unroll
                for (int mi = 0; mi < 2; mi++) pa[mi] = ldfrag(Pw, mi * 16 + lj, kk * 4 + hi);
#pragma unroll
                for (int nd = 0; nd < 4; nd++) bv[nd] = ldfrag(Vc, nd * 16 + lj, kk * 4 + hi);
#pragma unroll
                for (int mi = 0; mi < 2; mi++)
#pragma unroll
                    for (int nd = 0; nd < 4; nd++)
                        o[mi][nd] = __builtin_amdgcn_mfma_f32_16x16x32_bf16(pa[mi], bv[nd], o[mi][nd], 0, 0, 0);
            }
            __builtin_amdgcn_s_setprio(0);
        }

        LGKM0();
        SBAR(); SFENCE();
        cur ^= 1;
    }

    // ---- epilogue: x[b, srow, h*64+d] = O / l ----
    const int b_ = bh >> 4, h_ = bh & 15;
#pragma unroll
    for (int mi = 0; mi < 2; mi++)
#pragma unroll
        for (int r = 0; r < 4; r++) {
            float lv = __shfl(l_run[mi], (lane & 48) | (hi * 4 + r));
            float inv = 1.f / lv;
            const int srow = q0w + mi * 16 + hi * 4 + r;
#pragma unroll
            for (int nd = 0; nd < 4; nd++)
                Xb[((size_t)b_ * S + srow) * 1024 + h_ * 64 + nd * 16 + lj] =
                    f2bf(o[mi][nd][r] * inv);
        }
}

// ---------- launch ----------

extern "C" void kernel_launch(void* const* d_in, const int* in_sizes, int n_in,
                              void* d_out, int out_size, void* d_ws, size_t ws_size,
                              hipStream_t stream) {
    (void)in_sizes; (void)n_in; (void)out_size; (void)ws_size;
    const float* q  = (const float*)d_in[0];
    const float* k  = (const float*)d_in[1];
    const float* v  = (const float*)d_in[2];
    // d_in[3] = mask (causal tril) — computed analytically
    const float* Wq = (const float*)d_in[4];
    const float* Wk = (const float*)d_in[5];
    const float* Wv = (const float*)d_in[6];
    const float* Wo = (const float*)d_in[7];

    char* ws = (char*)d_ws;
    const size_t MB = (size_t)1 << 20;
    ushort* Qb  = (ushort*)(ws + 0 * MB);    // [2,16,2048,64] bf16
    ushort* Kb  = (ushort*)(ws + 8 * MB);    // [2,16,2048,64] bf16
    ushort* Vtb = (ushort*)(ws + 16 * MB);   // [2,16,64,2048] bf16
    ushort* Xb  = (ushort*)(ws + 24 * MB);   // [4096,1024]    bf16
    ushort* qb  = (ushort*)(ws + 32 * MB);
    ushort* kb  = (ushort*)(ws + 40 * MB);
    ushort* vb  = (ushort*)(ws + 48 * MB);
    ushort* Wqb = (ushort*)(ws + 56 * MB);
    ushort* Wkb = (ushort*)(ws + 58 * MB);
    ushort* Wvb = (ushort*)(ws + 60 * MB);
    ushort* Wob = (ushort*)(ws + 62 * MB);

    CvtArgs c;
    c.s[0] = q;  c.s[1] = k;  c.s[2] = v;  c.s[3] = Wq;  c.s[4] = Wk;  c.s[5] = Wv;  c.s[6] = Wo;
    c.d[0] = qb; c.d[1] = kb; c.d[2] = vb; c.d[3] = Wqb; c.d[4] = Wkb; c.d[5] = Wvb; c.d[6] = Wob;
    c.n[0] = c.n[1] = c.n[2] = 4 * 1024 * 1024;
    c.n[3] = c.n[4] = c.n[5] = c.n[6] = 1024 * 1024;
    cvt_kernel<<<dim3(1024, 7), 256, 0, stream>>>(c);

    ProjArgs p;
    p.A[0] = qb;  p.A[1] = kb;  p.A[2] = vb;
    p.W[0] = Wqb; p.W[1] = Wkb; p.W[2] = Wvb;
    p.O[0] = Qb;  p.O[1] = Kb;  p.O[2] = Vtb;
    p.scale[0] = 0.125f; p.scale[1] = 1.0f; p.scale[2] = 1.0f;
    p.mode[0] = 0; p.mode[1] = 0; p.mode[2] = 1;
    gemm_proj<<<dim3(512, 1, 3), 256, 0, stream>>>(p);

    attn_kernel<<<dim3(32, 16), 256, 0, stream>>>(Qb, Kb, Vtb, Xb);

    gemm_out<<<512, 256, 0, stream>>>(Xb, Wob, (float*)d_out);
}

// Round 4
// 261.980 us; speedup vs baseline: 1.2656x; 1.0793x over previous
//
#include <hip/hip_runtime.h>

typedef __bf16 bf16x8 __attribute__((ext_vector_type(8)));
typedef __bf16 bf16x2 __attribute__((ext_vector_type(2)));
typedef float  f32x4  __attribute__((ext_vector_type(4)));

#define DEV static __device__ __forceinline__
#define VMCNT(n) asm volatile("s_waitcnt vmcnt(" #n ")" ::: "memory")
#define LGKM0()  asm volatile("s_waitcnt lgkmcnt(0)" ::: "memory")
#define SBAR()   __builtin_amdgcn_s_barrier()
#define SFENCE() __builtin_amdgcn_sched_barrier(0)

// ---------- helpers ----------

DEV ushort f2bf(float f) {                     // RNE via native cvt
    return __builtin_bit_cast(ushort, (__bf16)f);
}
DEV uint pk2(float a, float b) {               // v_cvt_pk_bf16_f32
    bf16x2 t; t[0] = (__bf16)a; t[1] = (__bf16)b;
    return __builtin_bit_cast(uint, t);
}

// Stage an [nrows][64] bf16 tile (row stride gstride elems) into LDS via
// global_load_lds width=16; linear LDS dest, inverse-XOR-swizzled global source.
DEV void stage_swz(const ushort* g, int gstride, char* lds, int nchunks) {
    const int tid  = threadIdx.x;
    const int lane = tid & 63;
    const int wave = tid >> 6;
    for (int c0 = wave * 64; c0 < nchunks; c0 += 256) {
        int c   = c0 + lane;
        int row = c >> 3;
        int cc  = (c & 7) ^ (row & 7);
        const ushort* src = g + row * gstride + cc * 8;
        __builtin_amdgcn_global_load_lds((__attribute__((address_space(1))) void*)src,
                                         (__attribute__((address_space(3))) void*)(lds + c0 * 16),
                                         16, 0, 0);
    }
}

// Swizzled 16B fragment read: logical (row, 16B-chunk kc) of a [*][64] bf16 tile.
DEV bf16x8 ldfrag(const char* tile, int row, int kc) {
    int off = (row << 7) + ((kc ^ (row & 7)) << 4);
    return *(const bf16x8*)(tile + off);
}

// ---------- fp32 -> bf16 conversion (all 7 tensors, one dispatch) ----------

struct CvtArgs { const float* s[7]; ushort* d[7]; int n[7]; };

__global__ void cvt_kernel(CvtArgs a) {
    const int y = blockIdx.y;
    const float* __restrict__ s = a.s[y];
    ushort* __restrict__ d = a.d[y];
    const int n = a.n[y];
    const int stride = gridDim.x * blockDim.x;
    for (int i = blockIdx.x * blockDim.x + threadIdx.x; i * 8 < n; i += stride) {
        const float4* p = (const float4*)(s + (size_t)i * 8);
        float4 x = p[0], yv = p[1];
        uint4 o;
        o.x = pk2(x.x,  x.y);
        o.y = pk2(x.z,  x.w);
        o.z = pk2(yv.x, yv.y);
        o.w = pk2(yv.z, yv.w);
        *(uint4*)(d + (size_t)i * 8) = o;
    }
}

// ---------- GEMM core: y = A[4096,1024] @ W[1024,1024]^T ----------
// BM=128 BN=128 BK=64, 4 waves (2x2, 64x64 each), double-buffered LDS,
// counted vmcnt(8) (8 global_load_lds per thread per K-step).

constexpr int GN = 1024, GK = 1024;

template<typename EPI>
DEV void gemm_body(const ushort* __restrict__ A, const ushort* __restrict__ W,
                   char* smem, EPI epi) {
    const int tid  = threadIdx.x;
    const int lane = tid & 63;
    const int w    = tid >> 6;
    const int wr   = w >> 1, wc = w & 1;
    const int hi   = lane >> 4, lj = lane & 15;
    const int nb   = blockIdx.x & 7, mb = blockIdx.x >> 3;   // 8 n-tiles x 32 m-tiles

    f32x4 acc[4][4];
#pragma unroll
    for (int mi = 0; mi < 4; mi++)
#pragma unroll
        for (int ni = 0; ni < 4; ni++) acc[mi][ni] = f32x4{0.f, 0.f, 0.f, 0.f};

    const ushort* Ag = A + (size_t)mb * 128 * GK;
    const ushort* Wg = W + (size_t)nb * 128 * GK;

    stage_swz(Ag, GK, smem, 1024);
    stage_swz(Wg, GK, smem + 32768, 1024);
    int cur = 0;
    for (int k0 = 0; k0 < GK; k0 += 64) {
        char* Ac = smem + (cur << 14);
        char* Wc = smem + 32768 + (cur << 14);
        if (k0 + 64 < GK) {
            stage_swz(Ag + k0 + 64, GK, smem + ((cur ^ 1) << 14), 1024);
            stage_swz(Wg + k0 + 64, GK, smem + 32768 + ((cur ^ 1) << 14), 1024);
            VMCNT(8);
        } else {
            VMCNT(0);
        }
        SBAR(); SFENCE();
#pragma unroll
        for (int kk = 0; kk < 2; ++kk) {
            bf16x8 a[4], b[4];
#pragma unroll
            for (int mi = 0; mi < 4; mi++) a[mi] = ldfrag(Ac, wr * 64 + mi * 16 + lj, kk * 4 + hi);
#pragma unroll
            for (int ni = 0; ni < 4; ni++) b[ni] = ldfrag(Wc, wc * 64 + ni * 16 + lj, kk * 4 + hi);
#pragma unroll
            for (int mi = 0; mi < 4; mi++)
#pragma unroll
                for (int ni = 0; ni < 4; ni++)
                    acc[mi][ni] = __builtin_amdgcn_mfma_f32_16x16x32_bf16(a[mi], b[ni], acc[mi][ni], 0, 0, 0);
        }
        LGKM0();
        SBAR(); SFENCE();
        cur ^= 1;
    }

#pragma unroll
    for (int mi = 0; mi < 4; mi++)
#pragma unroll
        for (int r = 0; r < 4; r++) {
            const int gm = mb * 128 + wr * 64 + mi * 16 + hi * 4 + r;
#pragma unroll
            for (int ni = 0; ni < 4; ni++) {
                const int gn = nb * 128 + wc * 64 + ni * 16 + lj;
                epi(gm, gn, acc[mi][ni][r]);
            }
        }
}

struct ProjArgs {
    const ushort* A[3]; const ushort* W[3]; ushort* O[3];
    float scale[3]; int mode[3];
};

__global__ __launch_bounds__(256) void gemm_proj(ProjArgs args) {
    __shared__ char smem[65536];
    const int z = blockIdx.z;
    const ushort* A = args.A[z];
    const ushort* W = args.W[z];
    ushort* Out = args.O[z];
    const float scale = args.scale[z];
    const int mode = args.mode[z];
    gemm_body(A, W, smem, [&](int gm, int gn, float v) {
        v *= scale;
        const int b_ = gm >> 11, s_ = gm & 2047;
        const int h_ = gn >> 6,  d_ = gn & 63;
        size_t off;
        if (mode == 0) off = (((size_t)b_ * 16 + h_) * 2048 + s_) * 64 + d_;
        else           off = (((size_t)b_ * 16 + h_) * 64 + d_) * 2048 + s_;
        Out[off] = f2bf(v);
    });
}

__global__ __launch_bounds__(256) void gemm_out(const ushort* __restrict__ A,
                                                const ushort* __restrict__ W,
                                                float* __restrict__ Out) {
    __shared__ char smem[65536];
    gemm_body(A, W, smem, [&](int gm, int gn, float v) {
        Out[(size_t)gm * GN + gn] = v;
    });
}

// ---------- Flash attention (causal), swapped QK^T, in-lane softmax ----------
// Q [B,H,S,64] bf16 (pre-scaled 0.125*log2e -> exp2-direct softmax) in registers;
// K,V^T double-buffered in LDS; per-wave P tile [32][64] bf16 (XOR-swizzled).
// 4 waves x 32 q rows. Longest causal blocks launch first (LPT).

__global__ __launch_bounds__(256) void attn_kernel(const ushort* __restrict__ Qb,
                                                   const ushort* __restrict__ Kb,
                                                   const ushort* __restrict__ Vt,
                                                   ushort* __restrict__ Xb) {
    constexpr int S = 2048;
    __shared__ char smem[49152];
    const int tid = threadIdx.x, lane = tid & 63, w = tid >> 6;
    const int hi = lane >> 4, lj = lane & 15;
    char* Pw = smem + 32768 + w * 4096;   // per-wave [32][64] bf16, swizzled
    const int bh = blockIdx.x;
    const int yraw = blockIdx.y;
    const int qt = (yraw < 8) ? 15 - yraw : yraw - 8;   // longest first
    const int q0 = qt * 128;
    const int q0w = q0 + w * 32;

    const ushort* Qg = Qb + (size_t)bh * S * 64;
    const ushort* Kg = Kb + (size_t)bh * S * 64;
    const ushort* Vg = Vt + (size_t)bh * 64 * S;

    // Q fragments in registers: q = q0w + mi*16 + lj, k = kk*32 + hi*8 + [0..8)
    bf16x8 qf[2][2];
#pragma unroll
    for (int mi = 0; mi < 2; mi++)
#pragma unroll
        for (int kk = 0; kk < 2; kk++)
            qf[mi][kk] = *(const bf16x8*)(Qg + (size_t)(q0w + mi * 16 + lj) * 64 + kk * 32 + hi * 8);

    f32x4 o[2][4];
    float m_run[2] = { -1e30f, -1e30f }, l_run[2] = { 0.f, 0.f };
#pragma unroll
    for (int mi = 0; mi < 2; mi++)
#pragma unroll
        for (int nd = 0; nd < 4; nd++) o[mi][nd] = f32x4{0.f, 0.f, 0.f, 0.f};

    const int nt = qt * 2 + 2;
    stage_swz(Kg, 64, smem, 512);
    stage_swz(Vg, S, smem + 16384, 512);
    int cur = 0;

    for (int t = 0; t < nt; ++t) {
        char* Kc = smem + (cur << 13);
        char* Vc = smem + 16384 + (cur << 13);
        if (t + 1 < nt) {
            stage_swz(Kg + (size_t)(t + 1) * 64 * 64, 64, smem + ((cur ^ 1) << 13), 512);
            stage_swz(Vg + (t + 1) * 64, S, smem + 16384 + ((cur ^ 1) << 13), 512);
            VMCNT(4);
        } else {
            VMCNT(0);
        }
        SBAR(); SFENCE();

        if (t * 64 <= q0w + 31) {                 // wave-uniform causal skip
            // ---- S^T = mfma(K, Q): lane holds S[kv=ni*16+hi*4+r][q=mi*16+lj] ----
            f32x4 sc[2][4];
#pragma unroll
            for (int mi = 0; mi < 2; mi++)
#pragma unroll
                for (int ni = 0; ni < 4; ni++) sc[mi][ni] = f32x4{0.f, 0.f, 0.f, 0.f};
            __builtin_amdgcn_s_setprio(1);
#pragma unroll
            for (int kk = 0; kk < 2; ++kk) {
                bf16x8 kf[4];
#pragma unroll
                for (int ni = 0; ni < 4; ni++) kf[ni] = ldfrag(Kc, ni * 16 + lj, kk * 4 + hi);
#pragma unroll
                for (int mi = 0; mi < 2; mi++)
#pragma unroll
                    for (int ni = 0; ni < 4; ni++)
                        sc[mi][ni] = __builtin_amdgcn_mfma_f32_16x16x32_bf16(kf[ni], qf[mi][kk], sc[mi][ni], 0, 0, 0);
            }
            __builtin_amdgcn_s_setprio(0);

            const bool diag = (t * 64 + 63 > q0w);
#pragma unroll
            for (int mi = 0; mi < 2; mi++) {
                const int q = q0w + mi * 16 + lj;
                if (diag) {
#pragma unroll
                    for (int ni = 0; ni < 4; ni++)
#pragma unroll
                        for (int r = 0; r < 4; r++)
                            if (t * 64 + ni * 16 + hi * 4 + r > q) sc[mi][ni][r] = -1e30f;
                }
                float mx = -1e30f;
#pragma unroll
                for (int ni = 0; ni < 4; ni++)
#pragma unroll
                    for (int r = 0; r < 4; r++) mx = fmaxf(mx, sc[mi][ni][r]);
                mx = fmaxf(mx, __shfl_xor(mx, 16));
                mx = fmaxf(mx, __shfl_xor(mx, 32));
                const float mo = m_run[mi];
                const bool defer = __all(mx <= mo + 8.f);   // T13 defer-max
                float mn, rs;
                if (defer) { mn = mo; rs = 1.f; }
                else { mn = fmaxf(mo, mx); rs = __builtin_exp2f(mo - mn); m_run[mi] = mn; }
                float ps = 0.f;
                const int row = mi * 16 + lj;
#pragma unroll
                for (int ni = 0; ni < 4; ni++) {
                    float p0 = __builtin_exp2f(sc[mi][ni][0] - mn);
                    float p1 = __builtin_exp2f(sc[mi][ni][1] - mn);
                    float p2 = __builtin_exp2f(sc[mi][ni][2] - mn);
                    float p3 = __builtin_exp2f(sc[mi][ni][3] - mn);
                    ps += (p0 + p1) + (p2 + p3);
                    uint2 pv; pv.x = pk2(p0, p1); pv.y = pk2(p2, p3);
                    const int c = ni * 2 + (hi >> 1);
                    *(uint2*)(Pw + row * 128 + ((c ^ (row & 7)) << 4) + ((hi & 1) << 3)) = pv;
                }
                ps += __shfl_xor(ps, 16);
                ps += __shfl_xor(ps, 32);
                if (defer) {
                    l_run[mi] += ps;
                } else {
                    l_run[mi] = l_run[mi] * rs + ps;
                    // broadcast rescale to O-layout rows (q = mi*16 + hi*4 + r)
#pragma unroll
                    for (int r = 0; r < 4; r++) {
                        float rr = __shfl(rs, (lane & 48) | (hi * 4 + r));
#pragma unroll
                        for (int nd = 0; nd < 4; nd++) o[mi][nd][r] *= rr;
                    }
                }
            }

            LGKM0(); SFENCE();   // P writes visible to cross-lane reads

            // ---- O += P V : mfma(P rows q, Vt rows d) ----
            __builtin_amdgcn_s_setprio(1);
#pragma unroll
            for (int kk = 0; kk < 2; ++kk) {
                bf16x8 pa[2], bv[4];
#pragma unroll
                for (int mi = 0; mi < 2; mi++) pa[mi] = ldfrag(Pw, mi * 16 + lj, kk * 4 + hi);
#pragma unroll
                for (int nd = 0; nd < 4; nd++) bv[nd] = ldfrag(Vc, nd * 16 + lj, kk * 4 + hi);
#pragma unroll
                for (int mi = 0; mi < 2; mi++)
#pragma unroll
                    for (int nd = 0; nd < 4; nd++)
                        o[mi][nd] = __builtin_amdgcn_mfma_f32_16x16x32_bf16(pa[mi], bv[nd], o[mi][nd], 0, 0, 0);
            }
            __builtin_amdgcn_s_setprio(0);
        }

        LGKM0();
        SBAR(); SFENCE();
        cur ^= 1;
    }

    // ---- epilogue: x[b, srow, h*64+d] = O / l ----
    const int b_ = bh >> 4, h_ = bh & 15;
#pragma unroll
    for (int mi = 0; mi < 2; mi++)
#pragma unroll
        for (int r = 0; r < 4; r++) {
            float lv = __shfl(l_run[mi], (lane & 48) | (hi * 4 + r));
            float inv = 1.f / lv;
            const int srow = q0w + mi * 16 + hi * 4 + r;
#pragma unroll
            for (int nd = 0; nd < 4; nd++)
                Xb[((size_t)b_ * S + srow) * 1024 + h_ * 64 + nd * 16 + lj] =
                    f2bf(o[mi][nd][r] * inv);
        }
}

// ---------- launch ----------

extern "C" void kernel_launch(void* const* d_in, const int* in_sizes, int n_in,
                              void* d_out, int out_size, void* d_ws, size_t ws_size,
                              hipStream_t stream) {
    (void)in_sizes; (void)n_in; (void)out_size; (void)ws_size;
    const float* q  = (const float*)d_in[0];
    const float* k  = (const float*)d_in[1];
    const float* v  = (const float*)d_in[2];
    // d_in[3] = mask (causal tril) — computed analytically
    const float* Wq = (const float*)d_in[4];
    const float* Wk = (const float*)d_in[5];
    const float* Wv = (const float*)d_in[6];
    const float* Wo = (const float*)d_in[7];

    char* ws = (char*)d_ws;
    const size_t MB = (size_t)1 << 20;
    ushort* Qb  = (ushort*)(ws + 0 * MB);    // [2,16,2048,64] bf16
    ushort* Kb  = (ushort*)(ws + 8 * MB);    // [2,16,2048,64] bf16
    ushort* Vtb = (ushort*)(ws + 16 * MB);   // [2,16,64,2048] bf16
    ushort* Xb  = (ushort*)(ws + 24 * MB);   // [4096,1024]    bf16
    ushort* qb  = (ushort*)(ws + 32 * MB);
    ushort* kb  = (ushort*)(ws + 40 * MB);
    ushort* vb  = (ushort*)(ws + 48 * MB);
    ushort* Wqb = (ushort*)(ws + 56 * MB);
    ushort* Wkb = (ushort*)(ws + 58 * MB);
    ushort* Wvb = (ushort*)(ws + 60 * MB);
    ushort* Wob = (ushort*)(ws + 62 * MB);

    CvtArgs c;
    c.s[0] = q;  c.s[1] = k;  c.s[2] = v;  c.s[3] = Wq;  c.s[4] = Wk;  c.s[5] = Wv;  c.s[6] = Wo;
    c.d[0] = qb; c.d[1] = kb; c.d[2] = vb; c.d[3] = Wqb; c.d[4] = Wkb; c.d[5] = Wvb; c.d[6] = Wob;
    c.n[0] = c.n[1] = c.n[2] = 4 * 1024 * 1024;
    c.n[3] = c.n[4] = c.n[5] = c.n[6] = 1024 * 1024;
    cvt_kernel<<<dim3(1024, 7), 256, 0, stream>>>(c);

    ProjArgs p;
    p.A[0] = qb;  p.A[1] = kb;  p.A[2] = vb;
    p.W[0] = Wqb; p.W[1] = Wkb; p.W[2] = Wvb;
    p.O[0] = Qb;  p.O[1] = Kb;  p.O[2] = Vtb;
    p.scale[0] = 0.125f * 1.44269504088896f;    // exp2-direct softmax
    p.scale[1] = 1.0f; p.scale[2] = 1.0f;
    p.mode[0] = 0; p.mode[1] = 0; p.mode[2] = 1;
    gemm_proj<<<dim3(256, 1, 3), 256, 0, stream>>>(p);

    attn_kernel<<<dim3(32, 16), 256, 0, stream>>>(Qb, Kb, Vtb, Xb);

    gemm_out<<<256, 256, 0, stream>>>(Xb, Wob, (float*)d_out);
}

// Round 6
// 255.947 us; speedup vs baseline: 1.2954x; 1.0236x over previous
//
#include <hip/hip_runtime.h>

typedef __bf16 bf16x8 __attribute__((ext_vector_type(8)));
typedef __bf16 bf16x2 __attribute__((ext_vector_type(2)));
typedef float  f32x4  __attribute__((ext_vector_type(4)));

#define DEV static __device__ __forceinline__
#define VMCNT(n) asm volatile("s_waitcnt vmcnt(" #n ")" ::: "memory")
#define LGKM0()  asm volatile("s_waitcnt lgkmcnt(0)" ::: "memory")
#define SBAR()   __builtin_amdgcn_s_barrier()
#define SFENCE() __builtin_amdgcn_sched_barrier(0)

// ---------- helpers ----------

DEV ushort f2bf(float f) {                     // RNE via native cvt
    return __builtin_bit_cast(ushort, (__bf16)f);
}
DEV uint pk2(float a, float b) {               // v_cvt_pk_bf16_f32
    bf16x2 t; t[0] = (__bf16)a; t[1] = (__bf16)b;
    return __builtin_bit_cast(uint, t);
}

// Reduce over lanes {l, l^16, l^32, l^48}. R4-proven shfl_xor form.
// (R5's inline-asm v_permlane*_swap broke: VALU->permlane hazard nops are not
// inserted around opaque inline asm; keep the builtin-free safe version.)
DEV float redmax4(float x) {
    x = fmaxf(x, __shfl_xor(x, 16));
    return fmaxf(x, __shfl_xor(x, 32));
}
DEV float redsum4(float x) {
    x += __shfl_xor(x, 16);
    return x + __shfl_xor(x, 32);
}

// Stage an [nrows][64] bf16 tile (row stride gstride elems) into LDS via
// global_load_lds width=16; linear LDS dest, inverse-XOR-swizzled global source.
DEV void stage_swz(const ushort* g, int gstride, char* lds, int nchunks) {
    const int tid  = threadIdx.x;
    const int lane = tid & 63;
    const int wave = tid >> 6;
    for (int c0 = wave * 64; c0 < nchunks; c0 += 256) {
        int c   = c0 + lane;
        int row = c >> 3;
        int cc  = (c & 7) ^ (row & 7);
        const ushort* src = g + row * gstride + cc * 8;
        __builtin_amdgcn_global_load_lds((__attribute__((address_space(1))) void*)src,
                                         (__attribute__((address_space(3))) void*)(lds + c0 * 16),
                                         16, 0, 0);
    }
}

// Swizzled 16B fragment read: logical (row, 16B-chunk kc) of a [*][64] bf16 tile.
DEV bf16x8 ldfrag(const char* tile, int row, int kc) {
    int off = (row << 7) + ((kc ^ (row & 7)) << 4);
    return *(const bf16x8*)(tile + off);
}

// ---------- fp32 -> bf16 conversion (all 7 tensors, one dispatch) ----------

struct CvtArgs { const float* s[7]; ushort* d[7]; int n[7]; };

__global__ void cvt_kernel(CvtArgs a) {
    const int y = blockIdx.y;
    const float* __restrict__ s = a.s[y];
    ushort* __restrict__ d = a.d[y];
    const int n = a.n[y];
    const int stride = gridDim.x * blockDim.x;
    for (int i = blockIdx.x * blockDim.x + threadIdx.x; i * 8 < n; i += stride) {
        const float4* p = (const float4*)(s + (size_t)i * 8);
        float4 x = p[0], yv = p[1];
        uint4 o;
        o.x = pk2(x.x,  x.y);
        o.y = pk2(x.z,  x.w);
        o.z = pk2(yv.x, yv.y);
        o.w = pk2(yv.z, yv.w);
        *(uint4*)(d + (size_t)i * 8) = o;
    }
}

// ---------- GEMM core: y = A[4096,1024] @ W[1024,1024]^T ----------
// m97 structure: BM=BN=128 BK=64, single-buffered 32KB LDS, 2 barriers/K-step,
// relies on 3 co-resident blocks/CU for overlap. 4 waves (2x2, 64x64 each).

constexpr int GN = 1024, GK = 1024;

template<typename EPI>
DEV void gemm_body(const ushort* __restrict__ A, const ushort* __restrict__ W,
                   char* smem, EPI epi) {
    const int tid  = threadIdx.x;
    const int lane = tid & 63;
    const int w    = tid >> 6;
    const int wr   = w >> 1, wc = w & 1;
    const int hi   = lane >> 4, lj = lane & 15;
    const int nb   = blockIdx.x & 7, mb = blockIdx.x >> 3;   // 8 n-tiles x 32 m-tiles

    f32x4 acc[4][4];
#pragma unroll
    for (int mi = 0; mi < 4; mi++)
#pragma unroll
        for (int ni = 0; ni < 4; ni++) acc[mi][ni] = f32x4{0.f, 0.f, 0.f, 0.f};

    const ushort* Ag = A + (size_t)mb * 128 * GK;
    const ushort* Wg = W + (size_t)nb * 128 * GK;

    for (int k0 = 0; k0 < GK; k0 += 64) {
        __syncthreads();                       // prev reads done before overwrite
        stage_swz(Ag + k0, GK, smem, 1024);
        stage_swz(Wg + k0, GK, smem + 16384, 1024);
        __syncthreads();                       // staging visible
#pragma unroll
        for (int kk = 0; kk < 2; ++kk) {
            bf16x8 a[4], b[4];
#pragma unroll
            for (int mi = 0; mi < 4; mi++) a[mi] = ldfrag(smem, wr * 64 + mi * 16 + lj, kk * 4 + hi);
#pragma unroll
            for (int ni = 0; ni < 4; ni++) b[ni] = ldfrag(smem + 16384, wc * 64 + ni * 16 + lj, kk * 4 + hi);
#pragma unroll
            for (int mi = 0; mi < 4; mi++)
#pragma unroll
                for (int ni = 0; ni < 4; ni++)
                    acc[mi][ni] = __builtin_amdgcn_mfma_f32_16x16x32_bf16(a[mi], b[ni], acc[mi][ni], 0, 0, 0);
        }
    }

#pragma unroll
    for (int mi = 0; mi < 4; mi++)
#pragma unroll
        for (int r = 0; r < 4; r++) {
            const int gm = mb * 128 + wr * 64 + mi * 16 + hi * 4 + r;
#pragma unroll
            for (int ni = 0; ni < 4; ni++) {
                const int gn = nb * 128 + wc * 64 + ni * 16 + lj;
                epi(gm, gn, acc[mi][ni][r]);
            }
        }
}

struct ProjArgs {
    const ushort* A[3]; const ushort* W[3]; ushort* O[3];
    float scale[3]; int mode[3];
};

__global__ __launch_bounds__(256, 3) void gemm_proj(ProjArgs args) {
    __shared__ char smem[32768];
    const int z = blockIdx.z;
    const ushort* A = args.A[z];
    const ushort* W = args.W[z];
    ushort* Out = args.O[z];
    const float scale = args.scale[z];
    const int mode = args.mode[z];
    gemm_body(A, W, smem, [&](int gm, int gn, float v) {
        v *= scale;
        const int b_ = gm >> 11, s_ = gm & 2047;
        const int h_ = gn >> 6,  d_ = gn & 63;
        size_t off;
        if (mode == 0) off = (((size_t)b_ * 16 + h_) * 2048 + s_) * 64 + d_;
        else           off = (((size_t)b_ * 16 + h_) * 64 + d_) * 2048 + s_;
        Out[off] = f2bf(v);
    });
}

__global__ __launch_bounds__(256, 3) void gemm_out(const ushort* __restrict__ A,
                                                   const ushort* __restrict__ W,
                                                   float* __restrict__ Out) {
    __shared__ char smem[32768];
    gemm_body(A, W, smem, [&](int gm, int gn, float v) {
        Out[(size_t)gm * GN + gn] = v;
    });
}

// ---------- Flash attention (causal), swapped QK^T, in-lane softmax ----------
// Q [B,H,S,64] bf16 (pre-scaled 0.125*log2e, exp2-direct) in registers;
// K,V^T double-buffered in LDS (counted vmcnt); per-wave P tile [32][64] bf16.
// Flash-decoding split: qt>=8 blocks are split into two KV-halves writing
// fp32 partials (o, m, l); a merge kernel combines. Grid dim3(32 bh, 24 slot),
// slots ordered longest-first (LPT).

__global__ __launch_bounds__(256, 3) void attn_kernel(const ushort* __restrict__ Qb,
                                                      const ushort* __restrict__ Kb,
                                                      const ushort* __restrict__ Vt,
                                                      ushort* __restrict__ Xb,
                                                      float* __restrict__ Opart,
                                                      float* __restrict__ Mlp) {
    constexpr int S = 2048;
    __shared__ char smem[49152];
    const int tid = threadIdx.x, lane = tid & 63, w = tid >> 6;
    const int hi = lane >> 4, lj = lane & 15;
    char* Pw = smem + 32768 + w * 4096;   // per-wave [32][64] bf16, swizzled
    const int bh = blockIdx.x;
    const int y = blockIdx.y;             // 0..23

    int qt, kts, kte, half;
    bool partial;
    if (y < 16) {                          // split halves of qt = 8..15
        qt = 15 - (y >> 1); half = y & 1; partial = true;
        if (half == 0) { kts = 0; kte = qt + 1; }
        else           { kts = qt + 1; kte = 2 * qt + 2; }
    } else {                               // whole blocks qt = 7..0
        qt = 23 - y; half = 0; partial = false;
        kts = 0; kte = 2 * qt + 2;
    }
    const int q0 = qt * 128;
    const int q0w = q0 + w * 32;

    const ushort* Qg = Qb + (size_t)bh * S * 64;
    const ushort* Kg = Kb + (size_t)bh * S * 64;
    const ushort* Vg = Vt + (size_t)bh * 64 * S;

    // Q fragments in registers: q = q0w + mi*16 + lj, k = kk*32 + hi*8 + [0..8)
    bf16x8 qf[2][2];
#pragma unroll
    for (int mi = 0; mi < 2; mi++)
#pragma unroll
        for (int kk = 0; kk < 2; kk++)
            qf[mi][kk] = *(const bf16x8*)(Qg + (size_t)(q0w + mi * 16 + lj) * 64 + kk * 32 + hi * 8);

    f32x4 o[2][4];
    float m_run[2] = { -1e30f, -1e30f }, l_run[2] = { 0.f, 0.f };
#pragma unroll
    for (int mi = 0; mi < 2; mi++)
#pragma unroll
        for (int nd = 0; nd < 4; nd++) o[mi][nd] = f32x4{0.f, 0.f, 0.f, 0.f};

    stage_swz(Kg + (size_t)kts * 64 * 64, 64, smem, 512);
    stage_swz(Vg + kts * 64, S, smem + 16384, 512);
    int cur = 0;

    for (int t = kts; t < kte; ++t) {
        char* Kc = smem + (cur << 13);
        char* Vc = smem + 16384 + (cur << 13);
        if (t + 1 < kte) {
            stage_swz(Kg + (size_t)(t + 1) * 64 * 64, 64, smem + ((cur ^ 1) << 13), 512);
            stage_swz(Vg + (t + 1) * 64, S, smem + 16384 + ((cur ^ 1) << 13), 512);
            VMCNT(4);
        } else {
            VMCNT(0);
        }
        SBAR(); SFENCE();

        if (t * 64 <= q0w + 31) {                 // wave-uniform causal skip
            // ---- S^T = mfma(K, Q): lane holds S[kv=ni*16+hi*4+r][q=mi*16+lj] ----
            f32x4 sc[2][4];
#pragma unroll
            for (int mi = 0; mi < 2; mi++)
#pragma unroll
                for (int ni = 0; ni < 4; ni++) sc[mi][ni] = f32x4{0.f, 0.f, 0.f, 0.f};
            __builtin_amdgcn_s_setprio(1);
#pragma unroll
            for (int kk = 0; kk < 2; ++kk) {
                bf16x8 kf[4];
#pragma unroll
                for (int ni = 0; ni < 4; ni++) kf[ni] = ldfrag(Kc, ni * 16 + lj, kk * 4 + hi);
#pragma unroll
                for (int mi = 0; mi < 2; mi++)
#pragma unroll
                    for (int ni = 0; ni < 4; ni++)
                        sc[mi][ni] = __builtin_amdgcn_mfma_f32_16x16x32_bf16(kf[ni], qf[mi][kk], sc[mi][ni], 0, 0, 0);
            }
            __builtin_amdgcn_s_setprio(0);

            const bool diag = (t * 64 + 63 > q0w);
#pragma unroll
            for (int mi = 0; mi < 2; mi++) {
                const int q = q0w + mi * 16 + lj;
                if (diag) {
#pragma unroll
                    for (int ni = 0; ni < 4; ni++)
#pragma unroll
                        for (int r = 0; r < 4; r++)
                            if (t * 64 + ni * 16 + hi * 4 + r > q) sc[mi][ni][r] = -1e30f;
                }
                float mx = -1e30f;
#pragma unroll
                for (int ni = 0; ni < 4; ni++)
#pragma unroll
                    for (int r = 0; r < 4; r++) mx = fmaxf(mx, sc[mi][ni][r]);
                mx = redmax4(mx);
                const float mo = m_run[mi];
                const bool defer = __all(mx <= mo + 8.f);   // T13 defer-max
                float mn, rs;
                if (defer) { mn = mo; rs = 1.f; }
                else { mn = fmaxf(mo, mx); rs = __builtin_exp2f(mo - mn); m_run[mi] = mn; }
                float ps = 0.f;
                const int row = mi * 16 + lj;
#pragma unroll
                for (int ni = 0; ni < 4; ni++) {
                    float p0 = __builtin_exp2f(sc[mi][ni][0] - mn);
                    float p1 = __builtin_exp2f(sc[mi][ni][1] - mn);
                    float p2 = __builtin_exp2f(sc[mi][ni][2] - mn);
                    float p3 = __builtin_exp2f(sc[mi][ni][3] - mn);
                    ps += (p0 + p1) + (p2 + p3);
                    uint2 pv; pv.x = pk2(p0, p1); pv.y = pk2(p2, p3);
                    const int c = ni * 2 + (hi >> 1);
                    *(uint2*)(Pw + row * 128 + ((c ^ (row & 7)) << 4) + ((hi & 1) << 3)) = pv;
                }
                ps = redsum4(ps);
                if (defer) {
                    l_run[mi] += ps;
                } else {
                    l_run[mi] = l_run[mi] * rs + ps;
                    // broadcast rescale to O-layout rows (q = mi*16 + hi*4 + r)
#pragma unroll
                    for (int r = 0; r < 4; r++) {
                        float rr = __shfl(rs, (lane & 48) | (hi * 4 + r));
#pragma unroll
                        for (int nd = 0; nd < 4; nd++) o[mi][nd][r] *= rr;
                    }
                }
            }

            LGKM0(); SFENCE();   // P writes visible to cross-lane reads

            // ---- O += P V : mfma(P rows q, Vt rows d) ----
            __builtin_amdgcn_s_setprio(1);
#pragma unroll
            for (int kk = 0; kk < 2; ++kk) {
                bf16x8 pa[2], bv[4];
#pragma unroll
                for (int mi = 0; mi < 2; mi++) pa[mi] = ldfrag(Pw, mi * 16 + lj, kk * 4 + hi);
#pragma unroll
                for (int nd = 0; nd < 4; nd++) bv[nd] = ldfrag(Vc, nd * 16 + lj, kk * 4 + hi);
#pragma unroll
                for (int mi = 0; mi < 2; mi++)
#pragma unroll
                    for (int nd = 0; nd < 4; nd++)
                        o[mi][nd] = __builtin_amdgcn_mfma_f32_16x16x32_bf16(pa[mi], bv[nd], o[mi][nd], 0, 0, 0);
            }
            __builtin_amdgcn_s_setprio(0);
        }

        LGKM0();
        SBAR(); SFENCE();
        cur ^= 1;
    }

    if (partial) {
        // ---- store fp32 partials (o unnormalized, m, l) ----
        const int pidx = (((bh << 3) + (qt - 8)) << 1) + half;
        float* Op = Opart + (size_t)pidx * 8192;          // [128][64]
        float* Ml = Mlp   + (size_t)pidx * 256;           // [128][2]
#pragma unroll
        for (int mi = 0; mi < 2; mi++)
#pragma unroll
            for (int r = 0; r < 4; r++) {
                const int row = w * 32 + mi * 16 + hi * 4 + r;
#pragma unroll
                for (int nd = 0; nd < 4; nd++)
                    Op[row * 64 + nd * 16 + lj] = o[mi][nd][r];
            }
        if (hi == 0) {
#pragma unroll
            for (int mi = 0; mi < 2; mi++) {
                const int row = w * 32 + mi * 16 + lj;
                Ml[row * 2 + 0] = m_run[mi];
                Ml[row * 2 + 1] = l_run[mi];
            }
        }
    } else {
        // ---- epilogue: x[b, srow, h*64+d] = O / l ----
        const int b_ = bh >> 4, h_ = bh & 15;
#pragma unroll
        for (int mi = 0; mi < 2; mi++)
#pragma unroll
            for (int r = 0; r < 4; r++) {
                float lv = __shfl(l_run[mi], (lane & 48) | (hi * 4 + r));
                float inv = 1.f / lv;
                const int srow = q0w + mi * 16 + hi * 4 + r;
#pragma unroll
                for (int nd = 0; nd < 4; nd++)
                    Xb[((size_t)b_ * S + srow) * 1024 + h_ * 64 + nd * 16 + lj] =
                        f2bf(o[mi][nd][r] * inv);
            }
    }
}

// ---------- merge the two KV-halves for qt >= 8 ----------

__global__ __launch_bounds__(256) void attn_merge(const float* __restrict__ Op,
                                                  const float* __restrict__ Ml,
                                                  ushort* __restrict__ Xb) {
    const int bh = blockIdx.x;            // 32
    const int qt = 8 + blockIdx.y;        // 8..15
    const int tid = threadIdx.x;
    const int row = tid >> 1;
    const int c0 = (tid & 1) * 32;
    const int sbase = (((bh << 3) + (qt - 8)) << 1);
    const float* o0 = Op + (size_t)(sbase + 0) * 8192 + row * 64 + c0;
    const float* o1 = Op + (size_t)(sbase + 1) * 8192 + row * 64 + c0;
    const float* ml0 = Ml + (size_t)(sbase + 0) * 256 + row * 2;
    const float* ml1 = Ml + (size_t)(sbase + 1) * 256 + row * 2;
    const float m0 = ml0[0], l0 = ml0[1];
    const float m1 = ml1[0], l1 = ml1[1];
    const float m = fmaxf(m0, m1);
    const float a0 = __builtin_exp2f(m0 - m), a1 = __builtin_exp2f(m1 - m);
    const float inv = 1.f / (l0 * a0 + l1 * a1);
    const int b_ = bh >> 4, h_ = bh & 15;
    ushort* dst = Xb + ((size_t)b_ * 2048 + qt * 128 + row) * 1024 + h_ * 64 + c0;
#pragma unroll
    for (int c = 0; c < 32; c += 4) {
        float4 x = *(const float4*)(o0 + c);
        float4 y = *(const float4*)(o1 + c);
        uint2 pv;
        pv.x = pk2((x.x * a0 + y.x * a1) * inv, (x.y * a0 + y.y * a1) * inv);
        pv.y = pk2((x.z * a0 + y.z * a1) * inv, (x.w * a0 + y.w * a1) * inv);
        *(uint2*)(dst + c) = pv;
    }
}

// ---------- launch ----------

extern "C" void kernel_launch(void* const* d_in, const int* in_sizes, int n_in,
                              void* d_out, int out_size, void* d_ws, size_t ws_size,
                              hipStream_t stream) {
    (void)in_sizes; (void)n_in; (void)out_size; (void)ws_size;
    const float* q  = (const float*)d_in[0];
    const float* k  = (const float*)d_in[1];
    const float* v  = (const float*)d_in[2];
    // d_in[3] = mask (causal tril) — computed analytically
    const float* Wq = (const float*)d_in[4];
    const float* Wk = (const float*)d_in[5];
    const float* Wv = (const float*)d_in[6];
    const float* Wo = (const float*)d_in[7];

    char* ws = (char*)d_ws;
    const size_t MB = (size_t)1 << 20;
    ushort* Qb  = (ushort*)(ws + 0 * MB);    // [2,16,2048,64] bf16
    ushort* Kb  = (ushort*)(ws + 8 * MB);    // [2,16,2048,64] bf16
    ushort* Vtb = (ushort*)(ws + 16 * MB);   // [2,16,64,2048] bf16
    ushort* Xb  = (ushort*)(ws + 24 * MB);   // [4096,1024]    bf16
    ushort* qb  = (ushort*)(ws + 32 * MB);   // dead after gemm_proj
    ushort* kb  = (ushort*)(ws + 40 * MB);
    ushort* vb  = (ushort*)(ws + 48 * MB);
    ushort* Wqb = (ushort*)(ws + 56 * MB);
    ushort* Wkb = (ushort*)(ws + 58 * MB);
    ushort* Wvb = (ushort*)(ws + 60 * MB);
    ushort* Wob = (ushort*)(ws + 62 * MB);
    float*  Opart = (float*)(ws + 32 * MB);  // reuse qb/kb: 512 x 32KB = 16MB
    float*  Mlp   = (float*)(ws + 48 * MB);  // reuse vb: 512 x 1KB

    CvtArgs c;
    c.s[0] = q;  c.s[1] = k;  c.s[2] = v;  c.s[3] = Wq;  c.s[4] = Wk;  c.s[5] = Wv;  c.s[6] = Wo;
    c.d[0] = qb; c.d[1] = kb; c.d[2] = vb; c.d[3] = Wqb; c.d[4] = Wkb; c.d[5] = Wvb; c.d[6] = Wob;
    c.n[0] = c.n[1] = c.n[2] = 4 * 1024 * 1024;
    c.n[3] = c.n[4] = c.n[5] = c.n[6] = 1024 * 1024;
    cvt_kernel<<<dim3(1024, 7), 256, 0, stream>>>(c);

    ProjArgs p;
    p.A[0] = qb;  p.A[1] = kb;  p.A[2] = vb;
    p.W[0] = Wqb; p.W[1] = Wkb; p.W[2] = Wvb;
    p.O[0] = Qb;  p.O[1] = Kb;  p.O[2] = Vtb;
    p.scale[0] = 0.125f * 1.44269504088896f;    // exp2-direct softmax
    p.scale[1] = 1.0f; p.scale[2] = 1.0f;
    p.mode[0] = 0; p.mode[1] = 0; p.mode[2] = 1;
    gemm_proj<<<dim3(256, 1, 3), 256, 0, stream>>>(p);

    attn_kernel<<<dim3(32, 24), 256, 0, stream>>>(Qb, Kb, Vtb, Xb, Opart, Mlp);
    attn_merge<<<dim3(32, 8), 256, 0, stream>>>(Opart, Mlp, Xb);

    gemm_out<<<256, 256, 0, stream>>>(Xb, Wob, (float*)d_out);
}

// Round 7
// 248.300 us; speedup vs baseline: 1.3353x; 1.0308x over previous
//
#include <hip/hip_runtime.h>

typedef __bf16 bf16x8 __attribute__((ext_vector_type(8)));
typedef __bf16 bf16x2 __attribute__((ext_vector_type(2)));
typedef float  f32x4  __attribute__((ext_vector_type(4)));

#define DEV static __device__ __forceinline__
#define VMCNT(n) asm volatile("s_waitcnt vmcnt(" #n ")" ::: "memory")
#define LGKM0()  asm volatile("s_waitcnt lgkmcnt(0)" ::: "memory")
#define SBAR()   __builtin_amdgcn_s_barrier()
#define SFENCE() __builtin_amdgcn_sched_barrier(0)

// ---------- helpers ----------

DEV ushort f2bf(float f) {                     // RNE via native cvt
    return __builtin_bit_cast(ushort, (__bf16)f);
}
DEV uint pk2(float a, float b) {               // v_cvt_pk_bf16_f32
    bf16x2 t; t[0] = (__bf16)a; t[1] = (__bf16)b;
    return __builtin_bit_cast(uint, t);
}

// Reduce over lanes {l, l^16, l^32, l^48} (R4-proven shfl_xor form).
DEV float redmax4(float x) {
    x = fmaxf(x, __shfl_xor(x, 16));
    return fmaxf(x, __shfl_xor(x, 32));
}
DEV float redsum4(float x) {
    x += __shfl_xor(x, 16);
    return x + __shfl_xor(x, 32);
}

// Stage an [nrows][64] bf16 tile (row stride gstride elems) into LDS via
// global_load_lds width=16; linear LDS dest, inverse-XOR-swizzled global source.
DEV void stage_swz(const ushort* g, int gstride, char* lds, int nchunks) {
    const int tid  = threadIdx.x;
    const int lane = tid & 63;
    const int wave = tid >> 6;
    for (int c0 = wave * 64; c0 < nchunks; c0 += 256) {
        int c   = c0 + lane;
        int row = c >> 3;
        int cc  = (c & 7) ^ (row & 7);
        const ushort* src = g + row * gstride + cc * 8;
        __builtin_amdgcn_global_load_lds((__attribute__((address_space(1))) void*)src,
                                         (__attribute__((address_space(3))) void*)(lds + c0 * 16),
                                         16, 0, 0);
    }
}

// Same but for an [nrows][64] fp32 tile (16 chunks of 16B per row).
DEV void stage_swz32(const float* g, int gstride, char* lds, int nchunks) {
    const int tid  = threadIdx.x;
    const int lane = tid & 63;
    const int wave = tid >> 6;
    for (int c0 = wave * 64; c0 < nchunks; c0 += 256) {
        int c   = c0 + lane;
        int row = c >> 4;
        int cc  = (c & 15) ^ (row & 15);
        const float* src = g + row * gstride + cc * 4;
        __builtin_amdgcn_global_load_lds((__attribute__((address_space(1))) void*)src,
                                         (__attribute__((address_space(3))) void*)(lds + c0 * 16),
                                         16, 0, 0);
    }
}

// Swizzled 16B fragment read: logical (row, 16B-chunk kc) of a [*][64] bf16 tile.
DEV bf16x8 ldfrag(const char* tile, int row, int kc) {
    int off = (row << 7) + ((kc ^ (row & 7)) << 4);
    return *(const bf16x8*)(tile + off);
}

// fp32 tile -> bf16x8 fragment: reads logical fp32 chunks cl0, cl0+1 of row
// (row stride 256B, 16 chunks) and converts with cvt_pk.
DEV bf16x8 ldfrag32(const char* tile, int row, int cl0) {
    const int base = row << 8, rs = row & 15;
    f32x4 v0 = *(const f32x4*)(tile + base + ((cl0 ^ rs) << 4));
    f32x4 v1 = *(const f32x4*)(tile + base + (((cl0 + 1) ^ rs) << 4));
    uint4 u;
    u.x = pk2(v0[0], v0[1]); u.y = pk2(v0[2], v0[3]);
    u.z = pk2(v1[0], v1[1]); u.w = pk2(v1[2], v1[3]);
    return __builtin_bit_cast(bf16x8, u);
}

// ---------- fp32 -> bf16 conversion (weights only) ----------

struct CvtArgs { const float* s[4]; ushort* d[4]; int n; };

__global__ void cvt_kernel(CvtArgs a) {
    const float* __restrict__ s = a.s[blockIdx.y];
    ushort* __restrict__ d = a.d[blockIdx.y];
    const int stride = gridDim.x * blockDim.x;
    for (int i = blockIdx.x * blockDim.x + threadIdx.x; i * 8 < a.n; i += stride) {
        const float4* p = (const float4*)(s + (size_t)i * 8);
        float4 x = p[0], yv = p[1];
        uint4 o;
        o.x = pk2(x.x,  x.y);
        o.y = pk2(x.z,  x.w);
        o.z = pk2(yv.x, yv.y);
        o.w = pk2(yv.z, yv.w);
        *(uint4*)(d + (size_t)i * 8) = o;
    }
}

constexpr int GN = 1024, GK = 1024;

// ---------- proj GEMM: y = A_f32[4096,1024] @ W_bf16[1024,1024]^T ----------
// fp32 A staged directly (fused convert at frag load). BM=BN=128 BK=64,
// single-buffered 48KB LDS, 3 blocks/CU. XCD-chunked block swizzle.

struct ProjArgs {
    const float* A[3]; const ushort* W[3]; ushort* O[3];
    float scale[3]; int mode[3];
};

__global__ __launch_bounds__(256, 3) void gemm_proj(ProjArgs args) {
    __shared__ char smem[49152];                 // A f32 32KB + W bf16 16KB
    const int z = blockIdx.z;
    const float* A = args.A[z];
    const ushort* W = args.W[z];
    ushort* Out = args.O[z];
    const float scale = args.scale[z];
    const int mode = args.mode[z];

    const int tid  = threadIdx.x;
    const int lane = tid & 63;
    const int w    = tid >> 6;
    const int wr   = w >> 1, wc = w & 1;
    const int hi   = lane >> 4, lj = lane & 15;
    const int g    = blockIdx.x;
    const int o_   = ((g & 7) << 5) | (g >> 3);  // XCD-chunked: same-mb on one XCD
    const int nb   = o_ & 7, mb = o_ >> 3;

    f32x4 acc[4][4];
#pragma unroll
    for (int mi = 0; mi < 4; mi++)
#pragma unroll
        for (int ni = 0; ni < 4; ni++) acc[mi][ni] = f32x4{0.f, 0.f, 0.f, 0.f};

    const float*  Ag = A + (size_t)mb * 128 * GK;
    const ushort* Wg = W + (size_t)nb * 128 * GK;

    for (int k0 = 0; k0 < GK; k0 += 64) {
        __syncthreads();
        stage_swz32(Ag + k0, GK, smem, 2048);
        stage_swz(Wg + k0, GK, smem + 32768, 1024);
        __syncthreads();
#pragma unroll
        for (int kk = 0; kk < 2; ++kk) {
            bf16x8 a[4], b[4];
#pragma unroll
            for (int mi = 0; mi < 4; mi++) a[mi] = ldfrag32(smem, wr * 64 + mi * 16 + lj, kk * 8 + hi * 2);
#pragma unroll
            for (int ni = 0; ni < 4; ni++) b[ni] = ldfrag(smem + 32768, wc * 64 + ni * 16 + lj, kk * 4 + hi);
#pragma unroll
            for (int mi = 0; mi < 4; mi++)
#pragma unroll
                for (int ni = 0; ni < 4; ni++)
                    acc[mi][ni] = __builtin_amdgcn_mfma_f32_16x16x32_bf16(a[mi], b[ni], acc[mi][ni], 0, 0, 0);
        }
    }

#pragma unroll
    for (int mi = 0; mi < 4; mi++)
#pragma unroll
        for (int r = 0; r < 4; r++) {
            const int gm = mb * 128 + wr * 64 + mi * 16 + hi * 4 + r;
            const int b_ = gm >> 11, s_ = gm & 2047;
#pragma unroll
            for (int ni = 0; ni < 4; ni++) {
                const int gn = nb * 128 + wc * 64 + ni * 16 + lj;
                const int h_ = gn >> 6, d_ = gn & 63;
                float v = acc[mi][ni][r] * scale;
                size_t off;
                if (mode == 0) off = (((size_t)b_ * 16 + h_) * 2048 + s_) * 64 + d_;
                else           off = (((size_t)b_ * 16 + h_) * 64 + d_) * 2048 + s_;
                Out[off] = f2bf(v);
            }
        }
}

// ---------- out GEMM: bf16 A (m97 structure) ----------

__global__ __launch_bounds__(256, 3) void gemm_out(const ushort* __restrict__ A,
                                                   const ushort* __restrict__ W,
                                                   float* __restrict__ Out) {
    __shared__ char smem[32768];
    const int tid  = threadIdx.x;
    const int lane = tid & 63;
    const int w    = tid >> 6;
    const int wr   = w >> 1, wc = w & 1;
    const int hi   = lane >> 4, lj = lane & 15;
    const int g    = blockIdx.x;
    const int o_   = ((g & 7) << 5) | (g >> 3);
    const int nb   = o_ & 7, mb = o_ >> 3;

    f32x4 acc[4][4];
#pragma unroll
    for (int mi = 0; mi < 4; mi++)
#pragma unroll
        for (int ni = 0; ni < 4; ni++) acc[mi][ni] = f32x4{0.f, 0.f, 0.f, 0.f};

    const ushort* Ag = A + (size_t)mb * 128 * GK;
    const ushort* Wg = W + (size_t)nb * 128 * GK;

    for (int k0 = 0; k0 < GK; k0 += 64) {
        __syncthreads();
        stage_swz(Ag + k0, GK, smem, 1024);
        stage_swz(Wg + k0, GK, smem + 16384, 1024);
        __syncthreads();
#pragma unroll
        for (int kk = 0; kk < 2; ++kk) {
            bf16x8 a[4], b[4];
#pragma unroll
            for (int mi = 0; mi < 4; mi++) a[mi] = ldfrag(smem, wr * 64 + mi * 16 + lj, kk * 4 + hi);
#pragma unroll
            for (int ni = 0; ni < 4; ni++) b[ni] = ldfrag(smem + 16384, wc * 64 + ni * 16 + lj, kk * 4 + hi);
#pragma unroll
            for (int mi = 0; mi < 4; mi++)
#pragma unroll
                for (int ni = 0; ni < 4; ni++)
                    acc[mi][ni] = __builtin_amdgcn_mfma_f32_16x16x32_bf16(a[mi], b[ni], acc[mi][ni], 0, 0, 0);
        }
    }

#pragma unroll
    for (int mi = 0; mi < 4; mi++)
#pragma unroll
        for (int r = 0; r < 4; r++) {
            const int gm = mb * 128 + wr * 64 + mi * 16 + hi * 4 + r;
#pragma unroll
            for (int ni = 0; ni < 4; ni++) {
                const int gn = nb * 128 + wc * 64 + ni * 16 + lj;
                Out[(size_t)gm * GN + gn] = acc[mi][ni][r];
            }
        }
}

// ---------- Flash attention (causal), swapped QK^T, in-lane softmax ----------
// Slices of <=9 KV tiles: qt 12-15 x4, 8-11 x3, 4-7 x2, 0-3 whole.
// 40 slices/bh, LPT order. Partials (o bf16, m/l fp32) merged by attn_merge.

__global__ __launch_bounds__(256, 3) void attn_kernel(const ushort* __restrict__ Qb,
                                                      const ushort* __restrict__ Kb,
                                                      const ushort* __restrict__ Vt,
                                                      ushort* __restrict__ Xb,
                                                      ushort* __restrict__ Opart,
                                                      float* __restrict__ Mlp) {
    constexpr int S = 2048;
    __shared__ char smem[49152];
    const int tid = threadIdx.x, lane = tid & 63, w = tid >> 6;
    const int hi = lane >> 4, lj = lane & 15;
    char* Pw = smem + 32768 + w * 4096;   // per-wave [32][64] bf16, swizzled
    const int bh = blockIdx.x;
    const int y = blockIdx.y;             // 0..39, longest slices first

    int qt, slice, nsl;
    if (y < 16)      { qt = 12 + (y & 3);            slice = y >> 2;        nsl = 4; }
    else if (y < 28) { int zz = y - 16; qt = 8 + (zz & 3); slice = zz >> 2; nsl = 3; }
    else if (y < 36) { int zz = y - 28; qt = 4 + (zz & 3); slice = zz >> 2; nsl = 2; }
    else             { qt = y - 36;                  slice = 0;             nsl = 1; }
    const int nt  = 2 * qt + 2;
    const int kts = (nt * slice) / nsl;
    const int kte = (nt * (slice + 1)) / nsl;
    const bool partial = (nsl > 1);

    const int q0 = qt * 128;
    const int q0w = q0 + w * 32;

    const ushort* Qg = Qb + (size_t)bh * S * 64;
    const ushort* Kg = Kb + (size_t)bh * S * 64;
    const ushort* Vg = Vt + (size_t)bh * 64 * S;

    // Q fragments in registers: q = q0w + mi*16 + lj, k = kk*32 + hi*8 + [0..8)
    bf16x8 qf[2][2];
#pragma unroll
    for (int mi = 0; mi < 2; mi++)
#pragma unroll
        for (int kk = 0; kk < 2; kk++)
            qf[mi][kk] = *(const bf16x8*)(Qg + (size_t)(q0w + mi * 16 + lj) * 64 + kk * 32 + hi * 8);

    f32x4 o[2][4];
    float m_run[2] = { -1e30f, -1e30f }, l_run[2] = { 0.f, 0.f };
#pragma unroll
    for (int mi = 0; mi < 2; mi++)
#pragma unroll
        for (int nd = 0; nd < 4; nd++) o[mi][nd] = f32x4{0.f, 0.f, 0.f, 0.f};

    stage_swz(Kg + (size_t)kts * 64 * 64, 64, smem, 512);
    stage_swz(Vg + kts * 64, S, smem + 16384, 512);
    int cur = 0;

    for (int t = kts; t < kte; ++t) {
        char* Kc = smem + (cur << 13);
        char* Vc = smem + 16384 + (cur << 13);
        if (t + 1 < kte) {
            stage_swz(Kg + (size_t)(t + 1) * 64 * 64, 64, smem + ((cur ^ 1) << 13), 512);
            stage_swz(Vg + (t + 1) * 64, S, smem + 16384 + ((cur ^ 1) << 13), 512);
            VMCNT(4);
        } else {
            VMCNT(0);
        }
        SBAR(); SFENCE();

        if (t * 64 <= q0w + 31) {                 // wave-uniform causal skip
            // ---- S^T = mfma(K, Q): lane holds S[kv=ni*16+hi*4+r][q=mi*16+lj] ----
            f32x4 sc[2][4];
#pragma unroll
            for (int mi = 0; mi < 2; mi++)
#pragma unroll
                for (int ni = 0; ni < 4; ni++) sc[mi][ni] = f32x4{0.f, 0.f, 0.f, 0.f};
            __builtin_amdgcn_s_setprio(1);
#pragma unroll
            for (int kk = 0; kk < 2; ++kk) {
                bf16x8 kf[4];
#pragma unroll
                for (int ni = 0; ni < 4; ni++) kf[ni] = ldfrag(Kc, ni * 16 + lj, kk * 4 + hi);
#pragma unroll
                for (int mi = 0; mi < 2; mi++)
#pragma unroll
                    for (int ni = 0; ni < 4; ni++)
                        sc[mi][ni] = __builtin_amdgcn_mfma_f32_16x16x32_bf16(kf[ni], qf[mi][kk], sc[mi][ni], 0, 0, 0);
            }
            __builtin_amdgcn_s_setprio(0);

            const bool diag = (t * 64 + 63 > q0w);
#pragma unroll
            for (int mi = 0; mi < 2; mi++) {
                const int q = q0w + mi * 16 + lj;
                if (diag) {
#pragma unroll
                    for (int ni = 0; ni < 4; ni++)
#pragma unroll
                        for (int r = 0; r < 4; r++)
                            if (t * 64 + ni * 16 + hi * 4 + r > q) sc[mi][ni][r] = -1e30f;
                }
                float mx = -1e30f;
#pragma unroll
                for (int ni = 0; ni < 4; ni++)
#pragma unroll
                    for (int r = 0; r < 4; r++) mx = fmaxf(mx, sc[mi][ni][r]);
                mx = redmax4(mx);
                const float mo = m_run[mi];
                const bool defer = __all(mx <= mo + 8.f);   // T13 defer-max
                float mn, rs;
                if (defer) { mn = mo; rs = 1.f; }
                else { mn = fmaxf(mo, mx); rs = __builtin_exp2f(mo - mn); m_run[mi] = mn; }
                float ps = 0.f;
                const int row = mi * 16 + lj;
#pragma unroll
                for (int ni = 0; ni < 4; ni++) {
                    float p0 = __builtin_exp2f(sc[mi][ni][0] - mn);
                    float p1 = __builtin_exp2f(sc[mi][ni][1] - mn);
                    float p2 = __builtin_exp2f(sc[mi][ni][2] - mn);
                    float p3 = __builtin_exp2f(sc[mi][ni][3] - mn);
                    ps += (p0 + p1) + (p2 + p3);
                    uint2 pv; pv.x = pk2(p0, p1); pv.y = pk2(p2, p3);
                    const int c = ni * 2 + (hi >> 1);
                    *(uint2*)(Pw + row * 128 + ((c ^ (row & 7)) << 4) + ((hi & 1) << 3)) = pv;
                }
                ps = redsum4(ps);
                if (defer) {
                    l_run[mi] += ps;
                } else {
                    l_run[mi] = l_run[mi] * rs + ps;
                    // broadcast rescale to O-layout rows (q = mi*16 + hi*4 + r)
#pragma unroll
                    for (int r = 0; r < 4; r++) {
                        float rr = __shfl(rs, (lane & 48) | (hi * 4 + r));
#pragma unroll
                        for (int nd = 0; nd < 4; nd++) o[mi][nd][r] *= rr;
                    }
                }
            }

            LGKM0(); SFENCE();   // P writes visible to cross-lane reads

            // ---- O += P V : mfma(P rows q, Vt rows d) ----
            __builtin_amdgcn_s_setprio(1);
#pragma unroll
            for (int kk = 0; kk < 2; ++kk) {
                bf16x8 pa[2], bv[4];
#pragma unroll
                for (int mi = 0; mi < 2; mi++) pa[mi] = ldfrag(Pw, mi * 16 + lj, kk * 4 + hi);
#pragma unroll
                for (int nd = 0; nd < 4; nd++) bv[nd] = ldfrag(Vc, nd * 16 + lj, kk * 4 + hi);
#pragma unroll
                for (int mi = 0; mi < 2; mi++)
#pragma unroll
                    for (int nd = 0; nd < 4; nd++)
                        o[mi][nd] = __builtin_amdgcn_mfma_f32_16x16x32_bf16(pa[mi], bv[nd], o[mi][nd], 0, 0, 0);
            }
            __builtin_amdgcn_s_setprio(0);
        }

        LGKM0();
        SBAR(); SFENCE();
        cur ^= 1;
    }

    if (partial) {
        // ---- store partials: o (bf16, unnormalized), m, l (fp32) ----
        const int pidx = bh * 40 + y;
        ushort* Op = Opart + (size_t)pidx * 8192;         // [128][64] bf16
        float*  Ml = Mlp   + (size_t)pidx * 256;          // [128][2]
#pragma unroll
        for (int mi = 0; mi < 2; mi++)
#pragma unroll
            for (int r = 0; r < 4; r++) {
                const int row = w * 32 + mi * 16 + hi * 4 + r;
#pragma unroll
                for (int nd = 0; nd < 4; nd++)
                    Op[row * 64 + nd * 16 + lj] = f2bf(o[mi][nd][r]);
            }
        if (hi == 0) {
#pragma unroll
            for (int mi = 0; mi < 2; mi++) {
                const int row = w * 32 + mi * 16 + lj;
                Ml[row * 2 + 0] = m_run[mi];
                Ml[row * 2 + 1] = l_run[mi];
            }
        }
    } else {
        // ---- direct epilogue (qt < 4): x[b, srow, h*64+d] = O / l ----
        const int b_ = bh >> 4, h_ = bh & 15;
#pragma unroll
        for (int mi = 0; mi < 2; mi++)
#pragma unroll
            for (int r = 0; r < 4; r++) {
                float lv = __shfl(l_run[mi], (lane & 48) | (hi * 4 + r));
                float inv = 1.f / lv;
                const int srow = q0w + mi * 16 + hi * 4 + r;
#pragma unroll
                for (int nd = 0; nd < 4; nd++)
                    Xb[((size_t)b_ * S + srow) * 1024 + h_ * 64 + nd * 16 + lj] =
                        f2bf(o[mi][nd][r] * inv);
            }
    }
}

// ---------- merge the slices for qt >= 4 ----------

__global__ __launch_bounds__(256) void attn_merge(const ushort* __restrict__ Op,
                                                  const float* __restrict__ Ml,
                                                  ushort* __restrict__ Xb) {
    const int bh = blockIdx.x;            // 32
    const int qt = 4 + blockIdx.y;        // 4..15
    const int nsl  = (qt < 8) ? 2 : (qt < 12) ? 3 : 4;
    const int ybase = (qt >= 12) ? (qt - 12) : (qt >= 8) ? (16 + qt - 8) : (28 + qt - 4);
    const int tid = threadIdx.x;
    const int row = tid >> 1;
    const int c0 = (tid & 1) * 32;

    float ms[4], ls[4];
    float m = -1e30f;
    for (int s = 0; s < nsl; ++s) {
        const int slot = bh * 40 + ybase + s * 4;
        ms[s] = Ml[(size_t)slot * 256 + row * 2 + 0];
        ls[s] = Ml[(size_t)slot * 256 + row * 2 + 1];
        m = fmaxf(m, ms[s]);
    }
    float acc[32];
#pragma unroll
    for (int c = 0; c < 32; ++c) acc[c] = 0.f;
    float l = 0.f;
    for (int s = 0; s < nsl; ++s) {
        const float a = __builtin_exp2f(ms[s] - m);
        l += ls[s] * a;
        const ushort* op = Op + (size_t)(bh * 40 + ybase + s * 4) * 8192 + row * 64 + c0;
#pragma unroll
        for (int c8 = 0; c8 < 32; c8 += 8) {
            bf16x8 v = *(const bf16x8*)(op + c8);
#pragma unroll
            for (int e = 0; e < 8; ++e) acc[c8 + e] += a * (float)v[e];
        }
    }
    const float inv = 1.f / l;
    const int b_ = bh >> 4, h_ = bh & 15;
    ushort* dst = Xb + ((size_t)b_ * 2048 + qt * 128 + row) * 1024 + h_ * 64 + c0;
#pragma unroll
    for (int c = 0; c < 32; c += 2)
        *(uint*)(dst + c) = pk2(acc[c] * inv, acc[c + 1] * inv);
}

// ---------- launch ----------

extern "C" void kernel_launch(void* const* d_in, const int* in_sizes, int n_in,
                              void* d_out, int out_size, void* d_ws, size_t ws_size,
                              hipStream_t stream) {
    (void)in_sizes; (void)n_in; (void)out_size; (void)ws_size;
    const float* q  = (const float*)d_in[0];
    const float* k  = (const float*)d_in[1];
    const float* v  = (const float*)d_in[2];
    // d_in[3] = mask (causal tril) — computed analytically
    const float* Wq = (const float*)d_in[4];
    const float* Wk = (const float*)d_in[5];
    const float* Wv = (const float*)d_in[6];
    const float* Wo = (const float*)d_in[7];

    char* ws = (char*)d_ws;
    const size_t MB = (size_t)1 << 20;
    ushort* Qb   = (ushort*)(ws + 0 * MB);    // [2,16,2048,64] bf16
    ushort* Kb   = (ushort*)(ws + 8 * MB);    // [2,16,2048,64] bf16
    ushort* Vtb  = (ushort*)(ws + 16 * MB);   // [2,16,64,2048] bf16
    ushort* Xb   = (ushort*)(ws + 24 * MB);   // [4096,1024]    bf16
    ushort* Wqb  = (ushort*)(ws + 32 * MB);
    ushort* Wkb  = (ushort*)(ws + 34 * MB);
    ushort* Wvb  = (ushort*)(ws + 36 * MB);
    ushort* Wob  = (ushort*)(ws + 38 * MB);
    ushort* Opart= (ushort*)(ws + 40 * MB);   // 1280 x [128][64] bf16 = 20MB
    float*  Mlp  = (float*) (ws + 60 * MB);   // 1280 x [128][2] f32 = 1.25MB

    CvtArgs c;
    c.s[0] = Wq;  c.s[1] = Wk;  c.s[2] = Wv;  c.s[3] = Wo;
    c.d[0] = Wqb; c.d[1] = Wkb; c.d[2] = Wvb; c.d[3] = Wob;
    c.n = 1024 * 1024;
    cvt_kernel<<<dim3(512, 4), 256, 0, stream>>>(c);

    ProjArgs p;
    p.A[0] = q;   p.A[1] = k;   p.A[2] = v;
    p.W[0] = Wqb; p.W[1] = Wkb; p.W[2] = Wvb;
    p.O[0] = Qb;  p.O[1] = Kb;  p.O[2] = Vtb;
    p.scale[0] = 0.125f * 1.44269504088896f;    // exp2-direct softmax
    p.scale[1] = 1.0f; p.scale[2] = 1.0f;
    p.mode[0] = 0; p.mode[1] = 0; p.mode[2] = 1;
    gemm_proj<<<dim3(256, 1, 3), 256, 0, stream>>>(p);

    attn_kernel<<<dim3(32, 40), 256, 0, stream>>>(Qb, Kb, Vtb, Xb, Opart, Mlp);
    attn_merge<<<dim3(32, 12), 256, 0, stream>>>(Opart, Mlp, Xb);

    gemm_out<<<256, 256, 0, stream>>>(Xb, Wob, (float*)d_out);
}

// Round 8
// 237.915 us; speedup vs baseline: 1.3936x; 1.0436x over previous
//
#include <hip/hip_runtime.h>

typedef __bf16 bf16x8 __attribute__((ext_vector_type(8)));
typedef __bf16 bf16x2 __attribute__((ext_vector_type(2)));
typedef float  f32x4  __attribute__((ext_vector_type(4)));

#define DEV static __device__ __forceinline__
#define VMCNT(n) asm volatile("s_waitcnt vmcnt(" #n ")" ::: "memory")
#define LGKM0()  asm volatile("s_waitcnt lgkmcnt(0)" ::: "memory")
#define SBAR()   __builtin_amdgcn_s_barrier()
#define SFENCE() __builtin_amdgcn_sched_barrier(0)

// ---------- helpers ----------

DEV ushort f2bf(float f) {                     // RNE via native cvt
    return __builtin_bit_cast(ushort, (__bf16)f);
}
DEV uint pk2(float a, float b) {               // v_cvt_pk_bf16_f32
    bf16x2 t; t[0] = (__bf16)a; t[1] = (__bf16)b;
    return __builtin_bit_cast(uint, t);
}

// Reduce over lanes {l, l^16, l^32, l^48} (R4-proven shfl_xor form).
DEV float redmax4(float x) {
    x = fmaxf(x, __shfl_xor(x, 16));
    return fmaxf(x, __shfl_xor(x, 32));
}
DEV float redsum4(float x) {
    x += __shfl_xor(x, 16);
    return x + __shfl_xor(x, 32);
}

// Stage an [nrows][64] bf16 tile (row stride gstride elems) into LDS via
// global_load_lds width=16; linear LDS dest, inverse-XOR-swizzled global source.
DEV void stage_swz(const ushort* g, int gstride, char* lds, int nchunks) {
    const int tid  = threadIdx.x;
    const int lane = tid & 63;
    const int wave = tid >> 6;
    for (int c0 = wave * 64; c0 < nchunks; c0 += 256) {
        int c   = c0 + lane;
        int row = c >> 3;
        int cc  = (c & 7) ^ (row & 7);
        const ushort* src = g + row * gstride + cc * 8;
        __builtin_amdgcn_global_load_lds((__attribute__((address_space(1))) void*)src,
                                         (__attribute__((address_space(3))) void*)(lds + c0 * 16),
                                         16, 0, 0);
    }
}

// Swizzled 16B fragment read: logical (row, 16B-chunk kc) of a [*][64] bf16 tile.
DEV bf16x8 ldfrag(const char* tile, int row, int kc) {
    int off = (row << 7) + ((kc ^ (row & 7)) << 4);
    return *(const bf16x8*)(tile + off);
}

// ---------- fp32 -> bf16 conversion (all 7 tensors, one dispatch) ----------

struct CvtArgs { const float* s[7]; ushort* d[7]; int n[7]; };

__global__ void cvt_kernel(CvtArgs a) {
    const int y = blockIdx.y;
    const float* __restrict__ s = a.s[y];
    ushort* __restrict__ d = a.d[y];
    const int n = a.n[y];
    const int stride = gridDim.x * blockDim.x;
    for (int i = blockIdx.x * blockDim.x + threadIdx.x; i * 8 < n; i += stride) {
        const float4* p = (const float4*)(s + (size_t)i * 8);
        float4 x = p[0], yv = p[1];
        uint4 o;
        o.x = pk2(x.x,  x.y);
        o.y = pk2(x.z,  x.w);
        o.z = pk2(yv.x, yv.y);
        o.w = pk2(yv.z, yv.w);
        *(uint4*)(d + (size_t)i * 8) = o;
    }
}

constexpr int GN = 1024, GK = 1024;

// ---------- proj GEMM: y = A_bf16[4096,1024] @ W_bf16[1024,1024]^T ----------
// m97 structure: BM=BN=128 BK=64, single-buffered 32KB LDS, 2 barriers/K-step,
// 3 blocks/CU (grid 768). XCD-chunked block swizzle.

struct ProjArgs {
    const ushort* A[3]; const ushort* W[3]; ushort* O[3];
    float scale[3]; int mode[3];
};

__global__ __launch_bounds__(256, 3) void gemm_proj(ProjArgs args) {
    __shared__ char smem[32768];                 // A 16KB + W 16KB
    const int z = blockIdx.z;
    const ushort* A = args.A[z];
    const ushort* W = args.W[z];
    ushort* Out = args.O[z];
    const float scale = args.scale[z];
    const int mode = args.mode[z];

    const int tid  = threadIdx.x;
    const int lane = tid & 63;
    const int w    = tid >> 6;
    const int wr   = w >> 1, wc = w & 1;
    const int hi   = lane >> 4, lj = lane & 15;
    const int g    = blockIdx.x;
    const int o_   = ((g & 7) << 5) | (g >> 3);  // XCD-chunked: same-mb on one XCD
    const int nb   = o_ & 7, mb = o_ >> 3;

    f32x4 acc[4][4];
#pragma unroll
    for (int mi = 0; mi < 4; mi++)
#pragma unroll
        for (int ni = 0; ni < 4; ni++) acc[mi][ni] = f32x4{0.f, 0.f, 0.f, 0.f};

    const ushort* Ag = A + (size_t)mb * 128 * GK;
    const ushort* Wg = W + (size_t)nb * 128 * GK;

    for (int k0 = 0; k0 < GK; k0 += 64) {
        __syncthreads();
        stage_swz(Ag + k0, GK, smem, 1024);
        stage_swz(Wg + k0, GK, smem + 16384, 1024);
        __syncthreads();
#pragma unroll
        for (int kk = 0; kk < 2; ++kk) {
            bf16x8 a[4], b[4];
#pragma unroll
            for (int mi = 0; mi < 4; mi++) a[mi] = ldfrag(smem, wr * 64 + mi * 16 + lj, kk * 4 + hi);
#pragma unroll
            for (int ni = 0; ni < 4; ni++) b[ni] = ldfrag(smem + 16384, wc * 64 + ni * 16 + lj, kk * 4 + hi);
#pragma unroll
            for (int mi = 0; mi < 4; mi++)
#pragma unroll
                for (int ni = 0; ni < 4; ni++)
                    acc[mi][ni] = __builtin_amdgcn_mfma_f32_16x16x32_bf16(a[mi], b[ni], acc[mi][ni], 0, 0, 0);
        }
    }

#pragma unroll
    for (int mi = 0; mi < 4; mi++)
#pragma unroll
        for (int r = 0; r < 4; r++) {
            const int gm = mb * 128 + wr * 64 + mi * 16 + hi * 4 + r;
            const int b_ = gm >> 11, s_ = gm & 2047;
#pragma unroll
            for (int ni = 0; ni < 4; ni++) {
                const int gn = nb * 128 + wc * 64 + ni * 16 + lj;
                const int h_ = gn >> 6, d_ = gn & 63;
                float v = acc[mi][ni][r] * scale;
                size_t off;
                if (mode == 0) off = (((size_t)b_ * 16 + h_) * 2048 + s_) * 64 + d_;
                else           off = (((size_t)b_ * 16 + h_) * 64 + d_) * 2048 + s_;
                Out[off] = f2bf(v);
            }
        }
}

// ---------- out GEMM: BM=128 BN=64 (512 blocks = 2/CU), 24KB LDS ----------

__global__ __launch_bounds__(256, 3) void gemm_out(const ushort* __restrict__ A,
                                                   const ushort* __restrict__ W,
                                                   float* __restrict__ Out) {
    __shared__ char smem[24576];                 // A 16KB + W 8KB
    const int tid  = threadIdx.x;
    const int lane = tid & 63;
    const int w    = tid >> 6;
    const int wr   = w >> 1, wc = w & 1;
    const int hi   = lane >> 4, lj = lane & 15;
    const int g    = blockIdx.x;                 // 512 blocks
    const int o_   = ((g & 7) << 6) | (g >> 3);  // XCD-chunked
    const int nb   = o_ & 15, mb = o_ >> 4;      // 16 n-tiles x 32 m-tiles

    f32x4 acc[4][2];
#pragma unroll
    for (int mi = 0; mi < 4; mi++)
#pragma unroll
        for (int ni = 0; ni < 2; ni++) acc[mi][ni] = f32x4{0.f, 0.f, 0.f, 0.f};

    const ushort* Ag = A + (size_t)mb * 128 * GK;
    const ushort* Wg = W + (size_t)nb * 64 * GK;

    for (int k0 = 0; k0 < GK; k0 += 64) {
        __syncthreads();
        stage_swz(Ag + k0, GK, smem, 1024);
        stage_swz(Wg + k0, GK, smem + 16384, 512);
        __syncthreads();
#pragma unroll
        for (int kk = 0; kk < 2; ++kk) {
            bf16x8 a[4], b[2];
#pragma unroll
            for (int mi = 0; mi < 4; mi++) a[mi] = ldfrag(smem, wr * 64 + mi * 16 + lj, kk * 4 + hi);
#pragma unroll
            for (int ni = 0; ni < 2; ni++) b[ni] = ldfrag(smem + 16384, wc * 32 + ni * 16 + lj, kk * 4 + hi);
#pragma unroll
            for (int mi = 0; mi < 4; mi++)
#pragma unroll
                for (int ni = 0; ni < 2; ni++)
                    acc[mi][ni] = __builtin_amdgcn_mfma_f32_16x16x32_bf16(a[mi], b[ni], acc[mi][ni], 0, 0, 0);
        }
    }

#pragma unroll
    for (int mi = 0; mi < 4; mi++)
#pragma unroll
        for (int r = 0; r < 4; r++) {
            const int gm = mb * 128 + wr * 64 + mi * 16 + hi * 4 + r;
#pragma unroll
            for (int ni = 0; ni < 2; ni++) {
                const int gn = nb * 64 + wc * 32 + ni * 16 + lj;
                Out[(size_t)gm * GN + gn] = acc[mi][ni][r];
            }
        }
}

// ---------- Flash attention (causal), swapped QK^T, in-lane softmax ----------
// Slices of <=9 KV tiles: qt 12-15 x4, 8-11 x3, 4-7 x2, 0-3 whole.
// 40 slices/bh, LPT order. Partials (o bf16, m/l fp32) merged by attn_merge.

__global__ __launch_bounds__(256, 3) void attn_kernel(const ushort* __restrict__ Qb,
                                                      const ushort* __restrict__ Kb,
                                                      const ushort* __restrict__ Vt,
                                                      ushort* __restrict__ Xb,
                                                      ushort* __restrict__ Opart,
                                                      float* __restrict__ Mlp) {
    constexpr int S = 2048;
    __shared__ char smem[49152];
    const int tid = threadIdx.x, lane = tid & 63, w = tid >> 6;
    const int hi = lane >> 4, lj = lane & 15;
    char* Pw = smem + 32768 + w * 4096;   // per-wave [32][64] bf16, swizzled
    const int bh = blockIdx.x;
    const int y = blockIdx.y;             // 0..39, longest slices first

    int qt, slice, nsl;
    if (y < 16)      { qt = 12 + (y & 3);            slice = y >> 2;        nsl = 4; }
    else if (y < 28) { int zz = y - 16; qt = 8 + (zz & 3); slice = zz >> 2; nsl = 3; }
    else if (y < 36) { int zz = y - 28; qt = 4 + (zz & 3); slice = zz >> 2; nsl = 2; }
    else             { qt = y - 36;                  slice = 0;             nsl = 1; }
    const int nt  = 2 * qt + 2;
    const int kts = (nt * slice) / nsl;
    const int kte = (nt * (slice + 1)) / nsl;
    const bool partial = (nsl > 1);

    const int q0 = qt * 128;
    const int q0w = q0 + w * 32;

    const ushort* Qg = Qb + (size_t)bh * S * 64;
    const ushort* Kg = Kb + (size_t)bh * S * 64;
    const ushort* Vg = Vt + (size_t)bh * 64 * S;

    // Q fragments in registers: q = q0w + mi*16 + lj, k = kk*32 + hi*8 + [0..8)
    bf16x8 qf[2][2];
#pragma unroll
    for (int mi = 0; mi < 2; mi++)
#pragma unroll
        for (int kk = 0; kk < 2; kk++)
            qf[mi][kk] = *(const bf16x8*)(Qg + (size_t)(q0w + mi * 16 + lj) * 64 + kk * 32 + hi * 8);

    f32x4 o[2][4];
    float m_run[2] = { -1e30f, -1e30f }, l_run[2] = { 0.f, 0.f };
#pragma unroll
    for (int mi = 0; mi < 2; mi++)
#pragma unroll
        for (int nd = 0; nd < 4; nd++) o[mi][nd] = f32x4{0.f, 0.f, 0.f, 0.f};

    stage_swz(Kg + (size_t)kts * 64 * 64, 64, smem, 512);
    stage_swz(Vg + kts * 64, S, smem + 16384, 512);
    int cur = 0;

    for (int t = kts; t < kte; ++t) {
        char* Kc = smem + (cur << 13);
        char* Vc = smem + 16384 + (cur << 13);
        if (t + 1 < kte) {
            stage_swz(Kg + (size_t)(t + 1) * 64 * 64, 64, smem + ((cur ^ 1) << 13), 512);
            stage_swz(Vg + (t + 1) * 64, S, smem + 16384 + ((cur ^ 1) << 13), 512);
            VMCNT(4);
        } else {
            VMCNT(0);
        }
        SBAR(); SFENCE();

        if (t * 64 <= q0w + 31) {                 // wave-uniform causal skip
            // ---- S^T = mfma(K, Q): lane holds S[kv=ni*16+hi*4+r][q=mi*16+lj] ----
            f32x4 sc[2][4];
#pragma unroll
            for (int mi = 0; mi < 2; mi++)
#pragma unroll
                for (int ni = 0; ni < 4; ni++) sc[mi][ni] = f32x4{0.f, 0.f, 0.f, 0.f};
            __builtin_amdgcn_s_setprio(1);
#pragma unroll
            for (int kk = 0; kk < 2; ++kk) {
                bf16x8 kf[4];
#pragma unroll
                for (int ni = 0; ni < 4; ni++) kf[ni] = ldfrag(Kc, ni * 16 + lj, kk * 4 + hi);
#pragma unroll
                for (int mi = 0; mi < 2; mi++)
#pragma unroll
                    for (int ni = 0; ni < 4; ni++)
                        sc[mi][ni] = __builtin_amdgcn_mfma_f32_16x16x32_bf16(kf[ni], qf[mi][kk], sc[mi][ni], 0, 0, 0);
            }
            __builtin_amdgcn_s_setprio(0);

            const bool diag = (t * 64 + 63 > q0w);
#pragma unroll
            for (int mi = 0; mi < 2; mi++) {
                const int q = q0w + mi * 16 + lj;
                if (diag) {
#pragma unroll
                    for (int ni = 0; ni < 4; ni++)
#pragma unroll
                        for (int r = 0; r < 4; r++)
                            if (t * 64 + ni * 16 + hi * 4 + r > q) sc[mi][ni][r] = -1e30f;
                }
                float mx = -1e30f;
#pragma unroll
                for (int ni = 0; ni < 4; ni++)
#pragma unroll
                    for (int r = 0; r < 4; r++) mx = fmaxf(mx, sc[mi][ni][r]);
                mx = redmax4(mx);
                const float mo = m_run[mi];
                const bool defer = __all(mx <= mo + 8.f);   // T13 defer-max
                float mn, rs;
                if (defer) { mn = mo; rs = 1.f; }
                else { mn = fmaxf(mo, mx); rs = __builtin_exp2f(mo - mn); m_run[mi] = mn; }
                float ps = 0.f;
                const int row = mi * 16 + lj;
#pragma unroll
                for (int ni = 0; ni < 4; ni++) {
                    float p0 = __builtin_exp2f(sc[mi][ni][0] - mn);
                    float p1 = __builtin_exp2f(sc[mi][ni][1] - mn);
                    float p2 = __builtin_exp2f(sc[mi][ni][2] - mn);
                    float p3 = __builtin_exp2f(sc[mi][ni][3] - mn);
                    ps += (p0 + p1) + (p2 + p3);
                    uint2 pv; pv.x = pk2(p0, p1); pv.y = pk2(p2, p3);
                    const int c = ni * 2 + (hi >> 1);
                    *(uint2*)(Pw + row * 128 + ((c ^ (row & 7)) << 4) + ((hi & 1) << 3)) = pv;
                }
                ps = redsum4(ps);
                if (defer) {
                    l_run[mi] += ps;
                } else {
                    l_run[mi] = l_run[mi] * rs + ps;
                    // broadcast rescale to O-layout rows (q = mi*16 + hi*4 + r)
#pragma unroll
                    for (int r = 0; r < 4; r++) {
                        float rr = __shfl(rs, (lane & 48) | (hi * 4 + r));
#pragma unroll
                        for (int nd = 0; nd < 4; nd++) o[mi][nd][r] *= rr;
                    }
                }
            }

            LGKM0(); SFENCE();   // P writes visible to cross-lane reads

            // ---- O += P V : mfma(P rows q, Vt rows d) ----
            __builtin_amdgcn_s_setprio(1);
#pragma unroll
            for (int kk = 0; kk < 2; ++kk) {
                bf16x8 pa[2], bv[4];
#pragma unroll
                for (int mi = 0; mi < 2; mi++) pa[mi] = ldfrag(Pw, mi * 16 + lj, kk * 4 + hi);
#pragma unroll
                for (int nd = 0; nd < 4; nd++) bv[nd] = ldfrag(Vc, nd * 16 + lj, kk * 4 + hi);
#pragma unroll
                for (int mi = 0; mi < 2; mi++)
#pragma unroll
                    for (int nd = 0; nd < 4; nd++)
                        o[mi][nd] = __builtin_amdgcn_mfma_f32_16x16x32_bf16(pa[mi], bv[nd], o[mi][nd], 0, 0, 0);
            }
            __builtin_amdgcn_s_setprio(0);
        }

        LGKM0();
        SBAR(); SFENCE();
        cur ^= 1;
    }

    if (partial) {
        // ---- store partials: o (bf16, unnormalized), m, l (fp32) ----
        const int pidx = bh * 40 + y;
        ushort* Op = Opart + (size_t)pidx * 8192;         // [128][64] bf16
        float*  Ml = Mlp   + (size_t)pidx * 256;          // [128][2]
#pragma unroll
        for (int mi = 0; mi < 2; mi++)
#pragma unroll
            for (int r = 0; r < 4; r++) {
                const int row = w * 32 + mi * 16 + hi * 4 + r;
#pragma unroll
                for (int nd = 0; nd < 4; nd++)
                    Op[row * 64 + nd * 16 + lj] = f2bf(o[mi][nd][r]);
            }
        if (hi == 0) {
#pragma unroll
            for (int mi = 0; mi < 2; mi++) {
                const int row = w * 32 + mi * 16 + lj;
                Ml[row * 2 + 0] = m_run[mi];
                Ml[row * 2 + 1] = l_run[mi];
            }
        }
    } else {
        // ---- direct epilogue (qt < 4): x[b, srow, h*64+d] = O / l ----
        const int b_ = bh >> 4, h_ = bh & 15;
#pragma unroll
        for (int mi = 0; mi < 2; mi++)
#pragma unroll
            for (int r = 0; r < 4; r++) {
                float lv = __shfl(l_run[mi], (lane & 48) | (hi * 4 + r));
                float inv = 1.f / lv;
                const int srow = q0w + mi * 16 + hi * 4 + r;
#pragma unroll
                for (int nd = 0; nd < 4; nd++)
                    Xb[((size_t)b_ * S + srow) * 1024 + h_ * 64 + nd * 16 + lj] =
                        f2bf(o[mi][nd][r] * inv);
            }
    }
}

// ---------- merge the slices for qt >= 4 ----------

__global__ __launch_bounds__(256) void attn_merge(const ushort* __restrict__ Op,
                                                  const float* __restrict__ Ml,
                                                  ushort* __restrict__ Xb) {
    const int bh = blockIdx.x;            // 32
    const int qt = 4 + blockIdx.y;        // 4..15
    const int nsl  = (qt < 8) ? 2 : (qt < 12) ? 3 : 4;
    const int ybase = (qt >= 12) ? (qt - 12) : (qt >= 8) ? (16 + qt - 8) : (28 + qt - 4);
    const int tid = threadIdx.x;
    const int row = tid >> 1;
    const int c0 = (tid & 1) * 32;

    float ms[4], ls[4];
    float m = -1e30f;
    for (int s = 0; s < nsl; ++s) {
        const int slot = bh * 40 + ybase + s * 4;
        ms[s] = Ml[(size_t)slot * 256 + row * 2 + 0];
        ls[s] = Ml[(size_t)slot * 256 + row * 2 + 1];
        m = fmaxf(m, ms[s]);
    }
    float acc[32];
#pragma unroll
    for (int c = 0; c < 32; ++c) acc[c] = 0.f;
    float l = 0.f;
    for (int s = 0; s < nsl; ++s) {
        const float a = __builtin_exp2f(ms[s] - m);
        l += ls[s] * a;
        const ushort* op = Op + (size_t)(bh * 40 + ybase + s * 4) * 8192 + row * 64 + c0;
#pragma unroll
        for (int c8 = 0; c8 < 32; c8 += 8) {
            bf16x8 v = *(const bf16x8*)(op + c8);
#pragma unroll
            for (int e = 0; e < 8; ++e) acc[c8 + e] += a * (float)v[e];
        }
    }
    const float inv = 1.f / l;
    const int b_ = bh >> 4, h_ = bh & 15;
    ushort* dst = Xb + ((size_t)b_ * 2048 + qt * 128 + row) * 1024 + h_ * 64 + c0;
#pragma unroll
    for (int c = 0; c < 32; c += 2)
        *(uint*)(dst + c) = pk2(acc[c] * inv, acc[c + 1] * inv);
}

// ---------- launch ----------

extern "C" void kernel_launch(void* const* d_in, const int* in_sizes, int n_in,
                              void* d_out, int out_size, void* d_ws, size_t ws_size,
                              hipStream_t stream) {
    (void)in_sizes; (void)n_in; (void)out_size; (void)ws_size;
    const float* q  = (const float*)d_in[0];
    const float* k  = (const float*)d_in[1];
    const float* v  = (const float*)d_in[2];
    // d_in[3] = mask (causal tril) — computed analytically
    const float* Wq = (const float*)d_in[4];
    const float* Wk = (const float*)d_in[5];
    const float* Wv = (const float*)d_in[6];
    const float* Wo = (const float*)d_in[7];

    char* ws = (char*)d_ws;
    const size_t MB = (size_t)1 << 20;
    ushort* Qb   = (ushort*)(ws + 0 * MB);    // [2,16,2048,64] bf16
    ushort* Kb   = (ushort*)(ws + 8 * MB);    // [2,16,2048,64] bf16
    ushort* Vtb  = (ushort*)(ws + 16 * MB);   // [2,16,64,2048] bf16
    ushort* Xb   = (ushort*)(ws + 24 * MB);   // [4096,1024]    bf16
    ushort* qb   = (ushort*)(ws + 32 * MB);   // dead after gemm_proj
    ushort* kb   = (ushort*)(ws + 40 * MB);
    ushort* vb   = (ushort*)(ws + 48 * MB);
    ushort* Wqb  = (ushort*)(ws + 56 * MB);
    ushort* Wkb  = (ushort*)(ws + 58 * MB);
    ushort* Wvb  = (ushort*)(ws + 60 * MB);
    ushort* Wob  = (ushort*)(ws + 62 * MB);
    ushort* Opart= (ushort*)(ws + 32 * MB);   // overlays qb/kb: 1280x8KB = 20MB
    float*  Mlp  = (float*) (ws + 52 * MB);   // overlays vb tail: 1.25MB

    CvtArgs c;
    c.s[0] = q;  c.s[1] = k;  c.s[2] = v;  c.s[3] = Wq;  c.s[4] = Wk;  c.s[5] = Wv;  c.s[6] = Wo;
    c.d[0] = qb; c.d[1] = kb; c.d[2] = vb; c.d[3] = Wqb; c.d[4] = Wkb; c.d[5] = Wvb; c.d[6] = Wob;
    c.n[0] = c.n[1] = c.n[2] = 4 * 1024 * 1024;
    c.n[3] = c.n[4] = c.n[5] = c.n[6] = 1024 * 1024;
    cvt_kernel<<<dim3(1024, 7), 256, 0, stream>>>(c);

    ProjArgs p;
    p.A[0] = qb;  p.A[1] = kb;  p.A[2] = vb;
    p.W[0] = Wqb; p.W[1] = Wkb; p.W[2] = Wvb;
    p.O[0] = Qb;  p.O[1] = Kb;  p.O[2] = Vtb;
    p.scale[0] = 0.125f * 1.44269504088896f;    // exp2-direct softmax
    p.scale[1] = 1.0f; p.scale[2] = 1.0f;
    p.mode[0] = 0; p.mode[1] = 0; p.mode[2] = 1;
    gemm_proj<<<dim3(256, 1, 3), 256, 0, stream>>>(p);

    attn_kernel<<<dim3(32, 40), 256, 0, stream>>>(Qb, Kb, Vtb, Xb, Opart, Mlp);
    attn_merge<<<dim3(32, 12), 256, 0, stream>>>(Opart, Mlp, Xb);

    gemm_out<<<512, 256, 0, stream>>>(Xb, Wob, (float*)d_out);
}